// Round 14
// baseline (806.947 us; speedup 1.0000x reference)
//
#include <hip/hip_runtime.h>
#include <hip/hip_bf16.h>

#define BB   16
#define SS   8192
#define DD   128
#define HH   256
#define NTOK (BB * SS)
#define TM   64
#define THREADS 512
#define NW   8
#define LRATE 0.1f
#define EPSV  1e-5f
#define XCST 264   // XC stride in shorts: [x(128)|c(128)|pad8]
#define HST  264   // Hb stride in shorts

typedef short  bfrag __attribute__((ext_vector_type(8)));   // 8 bf16 = 4 VGPR (MFMA A/B frag)
typedef float  f32x4 __attribute__((ext_vector_type(4)));   // MFMA C/D frag
typedef unsigned short u16;

__device__ __forceinline__ u16 f2bf(float x) {
    unsigned u = __float_as_uint(x);
    unsigned r = (u + 0x7FFFu + ((u >> 16) & 1u)) >> 16;   // RTN-even
    return (u16)r;
}

// packed 2xfloat -> 2xbf16 (v_cvt_pk_bf16_f32, RNE)
__device__ __forceinline__ unsigned pkbf(float lo, float hi) {
    __hip_bfloat162 h2 = __float22bfloat162_rn(make_float2(lo, hi));
    unsigned u; __builtin_memcpy(&u, &h2, 4); return u;
}

// ---- weight prep: fp32 [K][N] -> bf16 transposed [N][K] in ws ----
// layout (shorts): W1t[256][128] @0, W2t[128][256] @32768, Wg1t[256][256] @65536, Wg2t[128][256] @131072
__global__ void prep_weights(const float* __restrict__ W1, const float* __restrict__ W2,
                             const float* __restrict__ Wg1, const float* __restrict__ Wg2,
                             u16* __restrict__ wsw) {
    int i = blockIdx.x * 256 + threadIdx.x;   // 0 .. 163839
    if (i < 32768) { int n = i >> 7, k = i & 127; wsw[i] = f2bf(W1[k * 256 + n]); return; }
    i -= 32768;
    if (i < 32768) { int n = i >> 8, k = i & 255; wsw[32768 + n * 256 + k] = f2bf(W2[k * 128 + n]); return; }
    i -= 32768;
    if (i < 65536) { int n = i >> 8, k = i & 255; wsw[65536 + n * 256 + k] = f2bf(Wg1[k * 256 + n]); return; }
    i -= 65536;
    { int n = i >> 8, k = i & 255; wsw[131072 + n * 256 + k] = f2bf(Wg2[k * 128 + n]); }
}

__global__ __launch_bounds__(THREADS, 2)
void refine_iter(const float* __restrict__ cur, const float* __restrict__ emb,
                 float* __restrict__ outp,
                 const u16* __restrict__ w1t, const u16* __restrict__ w2t,
                 const u16* __restrict__ wg1t, const u16* __restrict__ wg2t,
                 const float* __restrict__ b1, const float* __restrict__ lng,
                 const float* __restrict__ lnb, const float* __restrict__ b2,
                 const float* __restrict__ bg1, const float* __restrict__ bg2)
{
    __shared__ __align__(16) u16 XC[TM][XCST];   // [x | context] bf16
    __shared__ __align__(16) u16 Hb[TM][HST];    // H (phase-B input) then R (phase-D input)
    __shared__ float red1[TM][NW];
    __shared__ float red2[TM][NW];

    const int t    = threadIdx.x;
    const int g0   = blockIdx.x * TM;
    const int lane = t & 63;
    const int wid  = t >> 6;              // 8 waves; each owns ALL 64 rows x a column slice
    const int l16  = lane & 15;
    const int lk8  = (lane >> 4) * 8;     // k-offset within a 32-chunk
    const int l4   = (lane >> 4) * 4;     // D-frag row offset
    const int nAC  = wid * 32;            // A/C col slice (32 wide, ct in {0,1})
    const int nBD  = wid * 16;            // B/D col slice (16 wide, single ct)

    // ---- stage x tile + context tile (fp32 -> bf16, packed cvt) ----
    #pragma unroll
    for (int k = 0; k < 4; ++k) {
        const int f = t + k * THREADS;    // [0,2048)
        const int m = f >> 5;             // row 0..63
        const int o = (f & 31) * 4;
        const int gt = g0 + m;
        const int s  = gt & (SS - 1);
        const int rowbase = gt - s;
        const int sp = (s == 0) ? 1 : s - 1;
        const int sn = (s == SS - 1) ? (SS - 2) : s + 1;
        const float4 xv = *(const float4*)(cur + (size_t)gt * DD + o);
        const float4 av = *(const float4*)(cur + (size_t)(rowbase + sp) * DD + o);
        const float4 bv = *(const float4*)(cur + (size_t)(rowbase + sn) * DD + o);
        uint2 xq; xq.x = pkbf(xv.x, xv.y); xq.y = pkbf(xv.z, xv.w);
        *(uint2*)&XC[m][o] = xq;
        uint2 cq;
        cq.x = pkbf(0.5f * (av.x + bv.x), 0.5f * (av.y + bv.y));
        cq.y = pkbf(0.5f * (av.z + bv.z), 0.5f * (av.w + bv.w));
        *(uint2*)&XC[m][128 + o] = cq;
    }
    __syncthreads();

    const f32x4 zf = {0.f, 0.f, 0.f, 0.f};
    float mu[4][4], rs[4][4];

    // ================= Phase A: Y1 = X @ W1 + b1  (64x256, K=128) =================
    {
        f32x4 acc[4][2];   // [rt][ct]
        #pragma unroll
        for (int rt = 0; rt < 4; ++rt) { acc[rt][0] = zf; acc[rt][1] = zf; }
        bfrag wb[8];       // ct(2) x ks(4), batched
        #pragma unroll
        for (int ct = 0; ct < 2; ++ct)
            #pragma unroll
            for (int ks = 0; ks < 4; ++ks)
                wb[ct * 4 + ks] = *(const bfrag*)(w1t + (size_t)(nAC + ct * 16 + l16) * 128 + ks * 32 + lk8);
        __builtin_amdgcn_sched_barrier(0);
        #pragma unroll
        for (int ks = 0; ks < 4; ++ks) {
            bfrag af[4];
            #pragma unroll
            for (int rt = 0; rt < 4; ++rt)
                af[rt] = *(const bfrag*)&XC[rt * 16 + l16][ks * 32 + lk8];
            #pragma unroll
            for (int ct = 0; ct < 2; ++ct)
                #pragma unroll
                for (int rt = 0; rt < 4; ++rt)
                    acc[rt][ct] = __builtin_amdgcn_mfma_f32_16x16x32_bf16(af[rt], wb[ct * 4 + ks], acc[rt][ct], 0, 0, 0);
        }
        // bias before LN stats
        #pragma unroll
        for (int ct = 0; ct < 2; ++ct) {
            const float bb = b1[nAC + ct * 16 + l16];
            #pragma unroll
            for (int rt = 0; rt < 4; ++rt)
                #pragma unroll
                for (int r = 0; r < 4; ++r) acc[rt][ct][r] += bb;
        }

        // ---- LN stats: 16-lane butterfly per row, cross-wave via red ----
        #pragma unroll
        for (int rt = 0; rt < 4; ++rt)
            #pragma unroll
            for (int r = 0; r < 4; ++r) {
                const float v0 = acc[rt][0][r], v1 = acc[rt][1][r];
                float a = v0 + v1;
                float q = v0 * v0 + v1 * v1;
                #pragma unroll
                for (int m = 1; m <= 8; m <<= 1) {
                    a += __shfl_xor(a, m);
                    q += __shfl_xor(q, m);
                }
                if (l16 == 0) {
                    red1[rt * 16 + l4 + r][wid] = a;
                    red2[rt * 16 + l4 + r][wid] = q;
                }
            }
        __syncthreads();
        #pragma unroll
        for (int rt = 0; rt < 4; ++rt)
            #pragma unroll
            for (int r = 0; r < 4; ++r) {
                const int row = rt * 16 + l4 + r;
                const float4 a0 = *(const float4*)&red1[row][0];
                const float4 a1 = *(const float4*)&red1[row][4];
                const float4 q0 = *(const float4*)&red2[row][0];
                const float4 q1 = *(const float4*)&red2[row][4];
                const float s1 = a0.x + a0.y + a0.z + a0.w + a1.x + a1.y + a1.z + a1.w;
                const float s2 = q0.x + q0.y + q0.z + q0.w + q1.x + q1.y + q1.z + q1.w;
                const float m_ = s1 * (1.f / (float)HH);
                mu[rt][r] = m_;
                rs[rt][r] = rsqrtf(s2 * (1.f / (float)HH) - m_ * m_ + EPSV);
            }

        // ---- normalize + affine + relu -> Hb (bf16, packed cvt) ----
        const float ga = lng[nAC + l16],      ba = lnb[nAC + l16];
        const float gb = lng[nAC + 16 + l16], bb2 = lnb[nAC + 16 + l16];
        #pragma unroll
        for (int rt = 0; rt < 4; ++rt)
            #pragma unroll
            for (int r = 0; r < 4; ++r) {
                const float h0 = fmaxf((acc[rt][0][r] - mu[rt][r]) * rs[rt][r] * ga + ba, 0.f);
                const float h1 = fmaxf((acc[rt][1][r] - mu[rt][r]) * rs[rt][r] * gb + bb2, 0.f);
                const unsigned p = pkbf(h0, h1);
                Hb[rt * 16 + l4 + r][nAC + l16]      = (u16)(p & 0xffffu);
                Hb[rt * 16 + l4 + r][nAC + 16 + l16] = (u16)(p >> 16);
            }
    }
    __syncthreads();

    // ================= Phase B: P = H @ W2 + b2 ; err = emb - P  (64x128, K=256) =================
    float errv[4][4];
    {
        float ep[4][4];    // emb prefetch - in flight under the MFMA burst
        #pragma unroll
        for (int rt = 0; rt < 4; ++rt)
            #pragma unroll
            for (int r = 0; r < 4; ++r)
                ep[rt][r] = emb[(size_t)(g0 + rt * 16 + l4 + r) * DD + nBD + l16];
        f32x4 acc[4];
        #pragma unroll
        for (int rt = 0; rt < 4; ++rt) acc[rt] = zf;
        bfrag wb[8];       // ks(8), batched
        #pragma unroll
        for (int ks = 0; ks < 8; ++ks)
            wb[ks] = *(const bfrag*)(w2t + (size_t)(nBD + l16) * 256 + ks * 32 + lk8);
        __builtin_amdgcn_sched_barrier(0);
        #pragma unroll
        for (int ks = 0; ks < 8; ++ks) {
            bfrag af[4];
            #pragma unroll
            for (int rt = 0; rt < 4; ++rt)
                af[rt] = *(const bfrag*)&Hb[rt * 16 + l16][ks * 32 + lk8];
            #pragma unroll
            for (int rt = 0; rt < 4; ++rt)
                acc[rt] = __builtin_amdgcn_mfma_f32_16x16x32_bf16(af[rt], wb[ks], acc[rt], 0, 0, 0);
        }
        const float bb = b2[nBD + l16];
        #pragma unroll
        for (int rt = 0; rt < 4; ++rt)
            #pragma unroll
            for (int r = 0; r < 4; ++r)
                errv[rt][r] = ep[rt][r] - (acc[rt][r] + bb);
    }

    // ================= Phase C: R = relu([X|C] @ Wg1 + bg1)  (64x256, K=256) =================
    {
        f32x4 acc[4][2];
        #pragma unroll
        for (int rt = 0; rt < 4; ++rt) { acc[rt][0] = zf; acc[rt][1] = zf; }
        bfrag wb[16];      // ct(2) x ks(8), batched
        #pragma unroll
        for (int ct = 0; ct < 2; ++ct)
            #pragma unroll
            for (int ks = 0; ks < 8; ++ks)
                wb[ct * 8 + ks] = *(const bfrag*)(wg1t + (size_t)(nAC + ct * 16 + l16) * 256 + ks * 32 + lk8);
        __builtin_amdgcn_sched_barrier(0);
        #pragma unroll
        for (int ks = 0; ks < 8; ++ks) {
            bfrag a0;
            a0 = *(const bfrag*)&XC[0 * 16 + l16][ks * 32 + lk8];
            bfrag a1 = *(const bfrag*)&XC[1 * 16 + l16][ks * 32 + lk8];
            bfrag a2 = *(const bfrag*)&XC[2 * 16 + l16][ks * 32 + lk8];
            bfrag a3 = *(const bfrag*)&XC[3 * 16 + l16][ks * 32 + lk8];
            #pragma unroll
            for (int ct = 0; ct < 2; ++ct) {
                acc[0][ct] = __builtin_amdgcn_mfma_f32_16x16x32_bf16(a0, wb[ct * 8 + ks], acc[0][ct], 0, 0, 0);
                acc[1][ct] = __builtin_amdgcn_mfma_f32_16x16x32_bf16(a1, wb[ct * 8 + ks], acc[1][ct], 0, 0, 0);
                acc[2][ct] = __builtin_amdgcn_mfma_f32_16x16x32_bf16(a2, wb[ct * 8 + ks], acc[2][ct], 0, 0, 0);
                acc[3][ct] = __builtin_amdgcn_mfma_f32_16x16x32_bf16(a3, wb[ct * 8 + ks], acc[3][ct], 0, 0, 0);
            }
        }
        __syncthreads();   // all waves done reading Hb (phase B) before overwrite
        const float bga = bg1[nAC + l16];
        const float bgb = bg1[nAC + 16 + l16];
        #pragma unroll
        for (int rt = 0; rt < 4; ++rt)
            #pragma unroll
            for (int r = 0; r < 4; ++r) {
                const float r0v = fmaxf(acc[rt][0][r] + bga, 0.f);
                const float r1v = fmaxf(acc[rt][1][r] + bgb, 0.f);
                const unsigned p = pkbf(r0v, r1v);
                Hb[rt * 16 + l4 + r][nAC + l16]      = (u16)(p & 0xffffu);
                Hb[rt * 16 + l4 + r][nAC + 16 + l16] = (u16)(p >> 16);
            }
    }
    __syncthreads();

    // ================= Phase D: G = R @ Wg2 + bg2 ; out = x + LR*sigmoid(G)*err =================
    {
        float cp[4][4];    // cur prefetch for the epilogue
        #pragma unroll
        for (int rt = 0; rt < 4; ++rt)
            #pragma unroll
            for (int r = 0; r < 4; ++r)
                cp[rt][r] = cur[(size_t)(g0 + rt * 16 + l4 + r) * DD + nBD + l16];
        f32x4 acc[4];
        #pragma unroll
        for (int rt = 0; rt < 4; ++rt) acc[rt] = zf;
        bfrag wb[8];
        #pragma unroll
        for (int ks = 0; ks < 8; ++ks)
            wb[ks] = *(const bfrag*)(wg2t + (size_t)(nBD + l16) * 256 + ks * 32 + lk8);
        __builtin_amdgcn_sched_barrier(0);
        #pragma unroll
        for (int ks = 0; ks < 8; ++ks) {
            bfrag af[4];
            #pragma unroll
            for (int rt = 0; rt < 4; ++rt)
                af[rt] = *(const bfrag*)&Hb[rt * 16 + l16][ks * 32 + lk8];
            #pragma unroll
            for (int rt = 0; rt < 4; ++rt)
                acc[rt] = __builtin_amdgcn_mfma_f32_16x16x32_bf16(af[rt], wb[ks], acc[rt], 0, 0, 0);
        }
        const float bb = bg2[nBD + l16];
        #pragma unroll
        for (int rt = 0; rt < 4; ++rt)
            #pragma unroll
            for (int r = 0; r < 4; ++r) {
                const float z = acc[rt][r] + bb;
                const float gate = 1.f / (1.f + __expf(-z));
                outp[(size_t)(g0 + rt * 16 + l4 + r) * DD + nBD + l16] = cp[rt][r] + LRATE * gate * errv[rt][r];
            }
    }
}

extern "C" void kernel_launch(void* const* d_in, const int* in_sizes, int n_in,
                              void* d_out, int out_size, void* d_ws, size_t ws_size,
                              hipStream_t stream) {
    const float* emb = (const float*)d_in[0];
    const float* W1  = (const float*)d_in[1];
    const float* b1  = (const float*)d_in[2];
    const float* lng = (const float*)d_in[3];
    const float* lnb = (const float*)d_in[4];
    const float* W2  = (const float*)d_in[5];
    const float* b2  = (const float*)d_in[6];
    const float* Wg1 = (const float*)d_in[7];
    const float* bg1 = (const float*)d_in[8];
    const float* Wg2 = (const float*)d_in[9];
    const float* bg2 = (const float*)d_in[10];
    float* out = (float*)d_out;

    u16*   wsw  = (u16*)d_ws;                          // 320 KB bf16 transposed weights
    float* ping = (float*)((char*)d_ws + (1 << 20));   // 64 MB refined scratch

    const u16* w1t  = wsw;
    const u16* w2t  = wsw + 32768;
    const u16* wg1t = wsw + 65536;
    const u16* wg2t = wsw + 131072;

    prep_weights<<<640, 256, 0, stream>>>(W1, W2, Wg1, Wg2, wsw);

    const dim3 grid(NTOK / TM);
    const dim3 block(THREADS);
    // refined chain: emb -> out -> ping -> out -> ping -> out
    refine_iter<<<grid, block, 0, stream>>>(emb,  emb, out,  w1t, w2t, wg1t, wg2t, b1, lng, lnb, b2, bg1, bg2);
    refine_iter<<<grid, block, 0, stream>>>(out,  emb, ping, w1t, w2t, wg1t, wg2t, b1, lng, lnb, b2, bg1, bg2);
    refine_iter<<<grid, block, 0, stream>>>(ping, emb, out,  w1t, w2t, wg1t, wg2t, b1, lng, lnb, b2, bg1, bg2);
    refine_iter<<<grid, block, 0, stream>>>(out,  emb, ping, w1t, w2t, wg1t, wg2t, b1, lng, lnb, b2, bg1, bg2);
    refine_iter<<<grid, block, 0, stream>>>(ping, emb, out,  w1t, w2t, wg1t, wg2t, b1, lng, lnb, b2, bg1, bg2);
}

// Round 15
// 676.586 us; speedup vs baseline: 1.1927x; 1.1927x over previous
//
#include <hip/hip_runtime.h>
#include <hip/hip_bf16.h>

#define BB   16
#define SS   8192
#define DD   128
#define HH   256
#define NTOK (BB * SS)
#define TM   128
#define THREADS 512
#define NW   8
#define NRT  8
#define LRATE 0.1f
#define EPSV  1e-5f
#define XCST 264   // XC stride in shorts: [x(128)|c(128)|pad8]
#define HST  264   // Hb stride in shorts

typedef short  bfrag __attribute__((ext_vector_type(8)));   // 8 bf16 = 4 VGPR (MFMA A/B frag)
typedef float  f32x4 __attribute__((ext_vector_type(4)));   // MFMA C/D frag
typedef unsigned short u16;

__device__ __forceinline__ u16 f2bf(float x) {
    unsigned u = __float_as_uint(x);
    unsigned r = (u + 0x7FFFu + ((u >> 16) & 1u)) >> 16;   // RTN-even
    return (u16)r;
}

// packed 2xfloat -> 2xbf16 (v_cvt_pk_bf16_f32, RNE)
__device__ __forceinline__ unsigned pkbf(float lo, float hi) {
    __hip_bfloat162 h2 = __float22bfloat162_rn(make_float2(lo, hi));
    unsigned u; __builtin_memcpy(&u, &h2, 4); return u;
}

// ---- weight prep: fp32 [K][N] -> bf16 transposed [N][K] in ws ----
// layout (shorts): W1t[256][128] @0, W2t[128][256] @32768, Wg1t[256][256] @65536, Wg2t[128][256] @131072
__global__ void prep_weights(const float* __restrict__ W1, const float* __restrict__ W2,
                             const float* __restrict__ Wg1, const float* __restrict__ Wg2,
                             u16* __restrict__ wsw) {
    int i = blockIdx.x * 256 + threadIdx.x;   // 0 .. 163839
    if (i < 32768) { int n = i >> 7, k = i & 127; wsw[i] = f2bf(W1[k * 256 + n]); return; }
    i -= 32768;
    if (i < 32768) { int n = i >> 8, k = i & 255; wsw[32768 + n * 256 + k] = f2bf(W2[k * 128 + n]); return; }
    i -= 32768;
    if (i < 65536) { int n = i >> 8, k = i & 255; wsw[65536 + n * 256 + k] = f2bf(Wg1[k * 256 + n]); return; }
    i -= 65536;
    { int n = i >> 8, k = i & 255; wsw[131072 + n * 256 + k] = f2bf(Wg2[k * 128 + n]); }
}

__global__ __launch_bounds__(THREADS, 2)
void refine_iter(const float* __restrict__ cur, const float* __restrict__ emb,
                 float* __restrict__ outp,
                 const u16* __restrict__ w1t, const u16* __restrict__ w2t,
                 const u16* __restrict__ wg1t, const u16* __restrict__ wg2t,
                 const float* __restrict__ b1, const float* __restrict__ lng,
                 const float* __restrict__ lnb, const float* __restrict__ b2,
                 const float* __restrict__ bg1, const float* __restrict__ bg2)
{
    __shared__ __align__(16) u16 XC[TM][XCST];   // [x | context] bf16 (67.6 KB)
    __shared__ __align__(16) u16 Hb[TM][HST];    // H (phase-B input) then R (phase-D input) (67.6 KB)
    __shared__ float red1[TM][NW];
    __shared__ float red2[TM][NW];

    const int t    = threadIdx.x;
    const int g0   = blockIdx.x * TM;
    const int lane = t & 63;
    const int wid  = t >> 6;              // 8 waves; each owns ALL 128 rows x a column slice
    const int l16  = lane & 15;
    const int lk8  = (lane >> 4) * 8;     // k-offset within a 32-chunk
    const int l4   = (lane >> 4) * 4;     // D-frag row offset
    const int nAC  = wid * 32;            // A/C col slice (32 wide, ct in {0,1})
    const int nBD  = wid * 16;            // B/D col slice (16 wide, single ct)

    // ---- stage x tile + context tile (fp32 -> bf16, packed cvt) ----
    #pragma unroll
    for (int k = 0; k < 8; ++k) {
        const int f = t + k * THREADS;    // [0,4096)
        const int m = f >> 5;             // row 0..127
        const int o = (f & 31) * 4;
        const int gt = g0 + m;
        const int s  = gt & (SS - 1);
        const int rowbase = gt - s;
        const int sp = (s == 0) ? 1 : s - 1;
        const int sn = (s == SS - 1) ? (SS - 2) : s + 1;
        const float4 xv = *(const float4*)(cur + (size_t)gt * DD + o);
        const float4 av = *(const float4*)(cur + (size_t)(rowbase + sp) * DD + o);
        const float4 bv = *(const float4*)(cur + (size_t)(rowbase + sn) * DD + o);
        uint2 xq; xq.x = pkbf(xv.x, xv.y); xq.y = pkbf(xv.z, xv.w);
        *(uint2*)&XC[m][o] = xq;
        uint2 cq;
        cq.x = pkbf(0.5f * (av.x + bv.x), 0.5f * (av.y + bv.y));
        cq.y = pkbf(0.5f * (av.z + bv.z), 0.5f * (av.w + bv.w));
        *(uint2*)&XC[m][128 + o] = cq;
    }
    __syncthreads();

    const f32x4 zf = {0.f, 0.f, 0.f, 0.f};
    float mu[NRT][4], rs[NRT][4];

    // ================= Phase A: Y1 = X @ W1 + b1  (128x256, K=128) =================
    {
        f32x4 acc[NRT][2];   // [rt][ct]
        #pragma unroll
        for (int rt = 0; rt < NRT; ++rt) { acc[rt][0] = zf; acc[rt][1] = zf; }
        bfrag wb[8];       // ct(2) x ks(4), batched
        #pragma unroll
        for (int ct = 0; ct < 2; ++ct)
            #pragma unroll
            for (int ks = 0; ks < 4; ++ks)
                wb[ct * 4 + ks] = *(const bfrag*)(w1t + (size_t)(nAC + ct * 16 + l16) * 128 + ks * 32 + lk8);
        __builtin_amdgcn_sched_barrier(0);
        #pragma unroll
        for (int ks = 0; ks < 4; ++ks) {
            bfrag af[NRT];
            #pragma unroll
            for (int rt = 0; rt < NRT; ++rt)
                af[rt] = *(const bfrag*)&XC[rt * 16 + l16][ks * 32 + lk8];
            #pragma unroll
            for (int ct = 0; ct < 2; ++ct)
                #pragma unroll
                for (int rt = 0; rt < NRT; ++rt)
                    acc[rt][ct] = __builtin_amdgcn_mfma_f32_16x16x32_bf16(af[rt], wb[ct * 4 + ks], acc[rt][ct], 0, 0, 0);
        }
        // bias before LN stats
        #pragma unroll
        for (int ct = 0; ct < 2; ++ct) {
            const float bb = b1[nAC + ct * 16 + l16];
            #pragma unroll
            for (int rt = 0; rt < NRT; ++rt)
                #pragma unroll
                for (int r = 0; r < 4; ++r) acc[rt][ct][r] += bb;
        }

        // ---- LN stats: 16-lane butterfly per row, cross-wave via red ----
        #pragma unroll
        for (int rt = 0; rt < NRT; ++rt)
            #pragma unroll
            for (int r = 0; r < 4; ++r) {
                const float v0 = acc[rt][0][r], v1 = acc[rt][1][r];
                float a = v0 + v1;
                float q = v0 * v0 + v1 * v1;
                #pragma unroll
                for (int m = 1; m <= 8; m <<= 1) {
                    a += __shfl_xor(a, m);
                    q += __shfl_xor(q, m);
                }
                if (l16 == 0) {
                    red1[rt * 16 + l4 + r][wid] = a;
                    red2[rt * 16 + l4 + r][wid] = q;
                }
            }
        __syncthreads();
        #pragma unroll
        for (int rt = 0; rt < NRT; ++rt)
            #pragma unroll
            for (int r = 0; r < 4; ++r) {
                const int row = rt * 16 + l4 + r;
                const float4 a0 = *(const float4*)&red1[row][0];
                const float4 a1 = *(const float4*)&red1[row][4];
                const float4 q0 = *(const float4*)&red2[row][0];
                const float4 q1 = *(const float4*)&red2[row][4];
                const float s1 = a0.x + a0.y + a0.z + a0.w + a1.x + a1.y + a1.z + a1.w;
                const float s2 = q0.x + q0.y + q0.z + q0.w + q1.x + q1.y + q1.z + q1.w;
                const float m_ = s1 * (1.f / (float)HH);
                mu[rt][r] = m_;
                rs[rt][r] = rsqrtf(s2 * (1.f / (float)HH) - m_ * m_ + EPSV);
            }

        // ---- normalize + affine + relu -> Hb (bf16, packed cvt) ----
        const float ga = lng[nAC + l16],      ba = lnb[nAC + l16];
        const float gb = lng[nAC + 16 + l16], bb2 = lnb[nAC + 16 + l16];
        #pragma unroll
        for (int rt = 0; rt < NRT; ++rt)
            #pragma unroll
            for (int r = 0; r < 4; ++r) {
                const float h0 = fmaxf((acc[rt][0][r] - mu[rt][r]) * rs[rt][r] * ga + ba, 0.f);
                const float h1 = fmaxf((acc[rt][1][r] - mu[rt][r]) * rs[rt][r] * gb + bb2, 0.f);
                const unsigned p = pkbf(h0, h1);
                Hb[rt * 16 + l4 + r][nAC + l16]      = (u16)(p & 0xffffu);
                Hb[rt * 16 + l4 + r][nAC + 16 + l16] = (u16)(p >> 16);
            }
    }
    __syncthreads();

    // ================= Phase B: P = H @ W2 + b2 ; err = emb - P  (128x128, K=256) =================
    float errv[NRT][4];
    {
        float ep[NRT][4];    // emb prefetch - in flight under the MFMA burst
        #pragma unroll
        for (int rt = 0; rt < NRT; ++rt)
            #pragma unroll
            for (int r = 0; r < 4; ++r)
                ep[rt][r] = emb[(size_t)(g0 + rt * 16 + l4 + r) * DD + nBD + l16];
        f32x4 acc[NRT];
        #pragma unroll
        for (int rt = 0; rt < NRT; ++rt) acc[rt] = zf;
        bfrag wb[8];       // ks(8), batched
        #pragma unroll
        for (int ks = 0; ks < 8; ++ks)
            wb[ks] = *(const bfrag*)(w2t + (size_t)(nBD + l16) * 256 + ks * 32 + lk8);
        __builtin_amdgcn_sched_barrier(0);
        #pragma unroll
        for (int ks = 0; ks < 8; ++ks) {
            bfrag af[NRT];
            #pragma unroll
            for (int rt = 0; rt < NRT; ++rt)
                af[rt] = *(const bfrag*)&Hb[rt * 16 + l16][ks * 32 + lk8];
            #pragma unroll
            for (int rt = 0; rt < NRT; ++rt)
                acc[rt] = __builtin_amdgcn_mfma_f32_16x16x32_bf16(af[rt], wb[ks], acc[rt], 0, 0, 0);
        }
        const float bb = b2[nBD + l16];
        #pragma unroll
        for (int rt = 0; rt < NRT; ++rt)
            #pragma unroll
            for (int r = 0; r < 4; ++r)
                errv[rt][r] = ep[rt][r] - (acc[rt][r] + bb);
    }

    // ================= Phase C: R = relu([X|C] @ Wg1 + bg1)  (128x256, K=256) =================
    {
        f32x4 acc[NRT][2];
        #pragma unroll
        for (int rt = 0; rt < NRT; ++rt) { acc[rt][0] = zf; acc[rt][1] = zf; }
        bfrag wb[16];      // ct(2) x ks(8), batched
        #pragma unroll
        for (int ct = 0; ct < 2; ++ct)
            #pragma unroll
            for (int ks = 0; ks < 8; ++ks)
                wb[ct * 8 + ks] = *(const bfrag*)(wg1t + (size_t)(nAC + ct * 16 + l16) * 256 + ks * 32 + lk8);
        __builtin_amdgcn_sched_barrier(0);
        #pragma unroll
        for (int ks = 0; ks < 8; ++ks) {
            bfrag af[NRT];
            #pragma unroll
            for (int rt = 0; rt < NRT; ++rt)
                af[rt] = *(const bfrag*)&XC[rt * 16 + l16][ks * 32 + lk8];
            #pragma unroll
            for (int ct = 0; ct < 2; ++ct)
                #pragma unroll
                for (int rt = 0; rt < NRT; ++rt)
                    acc[rt][ct] = __builtin_amdgcn_mfma_f32_16x16x32_bf16(af[rt], wb[ct * 8 + ks], acc[rt][ct], 0, 0, 0);
        }
        __syncthreads();   // all waves done reading Hb (phase B) before overwrite
        const float bga = bg1[nAC + l16];
        const float bgb = bg1[nAC + 16 + l16];
        #pragma unroll
        for (int rt = 0; rt < NRT; ++rt)
            #pragma unroll
            for (int r = 0; r < 4; ++r) {
                const float r0v = fmaxf(acc[rt][0][r] + bga, 0.f);
                const float r1v = fmaxf(acc[rt][1][r] + bgb, 0.f);
                const unsigned p = pkbf(r0v, r1v);
                Hb[rt * 16 + l4 + r][nAC + l16]      = (u16)(p & 0xffffu);
                Hb[rt * 16 + l4 + r][nAC + 16 + l16] = (u16)(p >> 16);
            }
    }
    __syncthreads();

    // ================= Phase D: G = R @ Wg2 + bg2 ; out = x + LR*sigmoid(G)*err =================
    {
        float cp[NRT][4];    // cur prefetch for the epilogue
        #pragma unroll
        for (int rt = 0; rt < NRT; ++rt)
            #pragma unroll
            for (int r = 0; r < 4; ++r)
                cp[rt][r] = cur[(size_t)(g0 + rt * 16 + l4 + r) * DD + nBD + l16];
        f32x4 acc[NRT];
        #pragma unroll
        for (int rt = 0; rt < NRT; ++rt) acc[rt] = zf;
        bfrag wb[8];
        #pragma unroll
        for (int ks = 0; ks < 8; ++ks)
            wb[ks] = *(const bfrag*)(wg2t + (size_t)(nBD + l16) * 256 + ks * 32 + lk8);
        __builtin_amdgcn_sched_barrier(0);
        #pragma unroll
        for (int ks = 0; ks < 8; ++ks) {
            bfrag af[NRT];
            #pragma unroll
            for (int rt = 0; rt < NRT; ++rt)
                af[rt] = *(const bfrag*)&Hb[rt * 16 + l16][ks * 32 + lk8];
            #pragma unroll
            for (int rt = 0; rt < NRT; ++rt)
                acc[rt] = __builtin_amdgcn_mfma_f32_16x16x32_bf16(af[rt], wb[ks], acc[rt], 0, 0, 0);
        }
        const float bb = bg2[nBD + l16];
        #pragma unroll
        for (int rt = 0; rt < NRT; ++rt)
            #pragma unroll
            for (int r = 0; r < 4; ++r) {
                const float z = acc[rt][r] + bb;
                const float gate = 1.f / (1.f + __expf(-z));
                outp[(size_t)(g0 + rt * 16 + l4 + r) * DD + nBD + l16] = cp[rt][r] + LRATE * gate * errv[rt][r];
            }
    }
}

extern "C" void kernel_launch(void* const* d_in, const int* in_sizes, int n_in,
                              void* d_out, int out_size, void* d_ws, size_t ws_size,
                              hipStream_t stream) {
    const float* emb = (const float*)d_in[0];
    const float* W1  = (const float*)d_in[1];
    const float* b1  = (const float*)d_in[2];
    const float* lng = (const float*)d_in[3];
    const float* lnb = (const float*)d_in[4];
    const float* W2  = (const float*)d_in[5];
    const float* b2  = (const float*)d_in[6];
    const float* Wg1 = (const float*)d_in[7];
    const float* bg1 = (const float*)d_in[8];
    const float* Wg2 = (const float*)d_in[9];
    const float* bg2 = (const float*)d_in[10];
    float* out = (float*)d_out;

    u16*   wsw  = (u16*)d_ws;                          // 320 KB bf16 transposed weights
    float* ping = (float*)((char*)d_ws + (1 << 20));   // 64 MB refined scratch

    const u16* w1t  = wsw;
    const u16* w2t  = wsw + 32768;
    const u16* wg1t = wsw + 65536;
    const u16* wg2t = wsw + 131072;

    prep_weights<<<640, 256, 0, stream>>>(W1, W2, Wg1, Wg2, wsw);

    const dim3 grid(NTOK / TM);
    const dim3 block(THREADS);
    // refined chain: emb -> out -> ping -> out -> ping -> out
    refine_iter<<<grid, block, 0, stream>>>(emb,  emb, out,  w1t, w2t, wg1t, wg2t, b1, lng, lnb, b2, bg1, bg2);
    refine_iter<<<grid, block, 0, stream>>>(out,  emb, ping, w1t, w2t, wg1t, wg2t, b1, lng, lnb, b2, bg1, bg2);
    refine_iter<<<grid, block, 0, stream>>>(ping, emb, out,  w1t, w2t, wg1t, wg2t, b1, lng, lnb, b2, bg1, bg2);
    refine_iter<<<grid, block, 0, stream>>>(out,  emb, ping, w1t, w2t, wg1t, wg2t, b1, lng, lnb, b2, bg1, bg2);
    refine_iter<<<grid, block, 0, stream>>>(ping, emb, out,  w1t, w2t, wg1t, wg2t, b1, lng, lnb, b2, bg1, bg2);
}

// Round 16
// 616.843 us; speedup vs baseline: 1.3082x; 1.0969x over previous
//
#include <hip/hip_runtime.h>
#include <hip/hip_bf16.h>

#define BB   16
#define SS   8192
#define DD   128
#define HH   256
#define NTOK (BB * SS)
#define TM   64
#define THREADS 256
#define LRATE 0.1f
#define EPSV  1e-5f
#define XCST 264   // XC stride in shorts: [x(128)|c(128)|pad8]; later reused to hold R[64][256]
#define HST  264   // Hb stride in shorts

typedef short  bfrag __attribute__((ext_vector_type(8)));   // 8 bf16 = 4 VGPR (MFMA A/B frag)
typedef float  f32x4 __attribute__((ext_vector_type(4)));   // MFMA C/D frag
typedef unsigned short u16;

__device__ __forceinline__ u16 f2bf(float x) {
    unsigned u = __float_as_uint(x);
    unsigned r = (u + 0x7FFFu + ((u >> 16) & 1u)) >> 16;   // RTN-even
    return (u16)r;
}

// packed 2xfloat -> 2xbf16 (v_cvt_pk_bf16_f32, RNE)
__device__ __forceinline__ unsigned pkbf(float lo, float hi) {
    __hip_bfloat162 h2 = __float22bfloat162_rn(make_float2(lo, hi));
    unsigned u; __builtin_memcpy(&u, &h2, 4); return u;
}

// ---- weight prep: fp32 [K][N] -> bf16 transposed [N][K] in ws ----
// layout (shorts): W1t[256][128] @0, W2t[128][256] @32768, Wg1t[256][256] @65536, Wg2t[128][256] @131072
__global__ void prep_weights(const float* __restrict__ W1, const float* __restrict__ W2,
                             const float* __restrict__ Wg1, const float* __restrict__ Wg2,
                             u16* __restrict__ wsw) {
    int i = blockIdx.x * 256 + threadIdx.x;   // 0 .. 163839
    if (i < 32768) { int n = i >> 7, k = i & 127; wsw[i] = f2bf(W1[k * 256 + n]); return; }
    i -= 32768;
    if (i < 32768) { int n = i >> 8, k = i & 255; wsw[32768 + n * 256 + k] = f2bf(W2[k * 128 + n]); return; }
    i -= 32768;
    if (i < 65536) { int n = i >> 8, k = i & 255; wsw[65536 + n * 256 + k] = f2bf(Wg1[k * 256 + n]); return; }
    i -= 65536;
    { int n = i >> 8, k = i & 255; wsw[131072 + n * 256 + k] = f2bf(Wg2[k * 128 + n]); }
}

__global__ __launch_bounds__(THREADS, 2)
void refine_iter(const float* __restrict__ cur, const float* __restrict__ emb,
                 float* __restrict__ outp,
                 const u16* __restrict__ w1t, const u16* __restrict__ w2t,
                 const u16* __restrict__ wg1t, const u16* __restrict__ wg2t,
                 const float* __restrict__ b1, const float* __restrict__ lng,
                 const float* __restrict__ lnb, const float* __restrict__ b2,
                 const float* __restrict__ bg1, const float* __restrict__ bg2)
{
    __shared__ __align__(16) u16 XC[TM][XCST];   // [x | context] bf16; after phase B holds R
    __shared__ __align__(16) u16 Hb[TM][HST];    // H (phase-B input)
    __shared__ float red1[TM][4];
    __shared__ float red2[TM][4];

    const int t    = threadIdx.x;
    const int g0   = blockIdx.x * TM;
    const int lane = t & 63;
    const int wid  = t >> 6;              // 4 waves; each owns ALL 64 rows x a column slice
    const int l16  = lane & 15;
    const int lk8  = (lane >> 4) * 8;     // k-offset within a 32-chunk
    const int l4   = (lane >> 4) * 4;     // D-frag row offset
    const int nAC  = wid * 64;            // A/C col slice (64 wide, ct 0..3)
    const int nBD  = wid * 32;            // B/D col slice (32 wide, ct 0..1)

    // ---- stage x tile + context tile (fp32 -> bf16, packed cvt) ----
    #pragma unroll
    for (int k = 0; k < 8; ++k) {
        const int f = t + k * THREADS;    // [0,2048)
        const int m = f >> 5;             // row 0..63
        const int o = (f & 31) * 4;
        const int gt = g0 + m;
        const int s  = gt & (SS - 1);
        const int rowbase = gt - s;
        const int sp = (s == 0) ? 1 : s - 1;
        const int sn = (s == SS - 1) ? (SS - 2) : s + 1;
        const float4 xv = *(const float4*)(cur + (size_t)gt * DD + o);
        const float4 av = *(const float4*)(cur + (size_t)(rowbase + sp) * DD + o);
        const float4 bv = *(const float4*)(cur + (size_t)(rowbase + sn) * DD + o);
        uint2 xq; xq.x = pkbf(xv.x, xv.y); xq.y = pkbf(xv.z, xv.w);
        *(uint2*)&XC[m][o] = xq;
        uint2 cq;
        cq.x = pkbf(0.5f * (av.x + bv.x), 0.5f * (av.y + bv.y));
        cq.y = pkbf(0.5f * (av.z + bv.z), 0.5f * (av.w + bv.w));
        *(uint2*)&XC[m][128 + o] = cq;
    }

    // ---- early prefetch: emb values needed by phase B (acc layout) ----
    float ep[4][2][4];
    #pragma unroll
    for (int rt = 0; rt < 4; ++rt)
        #pragma unroll
        for (int ct = 0; ct < 2; ++ct)
            #pragma unroll
            for (int r = 0; r < 4; ++r)
                ep[rt][ct][r] = emb[(size_t)(g0 + rt * 16 + l4 + r) * DD + nBD + ct * 16 + l16];
    __syncthreads();

    const f32x4 zf = {0.f, 0.f, 0.f, 0.f};
    float mu[4][4], rs[4][4];

    // ======== FUSED region: phase A (X@W1 -> accA) + phase C ([X|C]@Wg1 -> accC) ========
    // 192 MFMAs, no barrier inside; C's load batches overlap A's MFMA bursts.
    f32x4 accA[4][4];   // Y1 pre-LN
    f32x4 accC[4][4];   // gate hidden pre-relu (held in regs across LN and phase B)
    #pragma unroll
    for (int rt = 0; rt < 4; ++rt)
        #pragma unroll
        for (int ct = 0; ct < 4; ++ct) { accA[rt][ct] = zf; accC[rt][ct] = zf; }

    // ---- A: K=128 over x half ----
    #pragma unroll
    for (int h = 0; h < 2; ++h) {        // ct-pairs
        bfrag wb[8];                     // i(2) x ks(4), batched
        #pragma unroll
        for (int i = 0; i < 2; ++i)
            #pragma unroll
            for (int ks = 0; ks < 4; ++ks)
                wb[i * 4 + ks] = *(const bfrag*)(w1t + (size_t)(nAC + (h * 2 + i) * 16 + l16) * 128 + ks * 32 + lk8);
        __builtin_amdgcn_sched_barrier(0);
        #pragma unroll
        for (int ks = 0; ks < 4; ++ks) {
            bfrag af[4];
            #pragma unroll
            for (int rt = 0; rt < 4; ++rt)
                af[rt] = *(const bfrag*)&XC[rt * 16 + l16][ks * 32 + lk8];
            #pragma unroll
            for (int i = 0; i < 2; ++i)
                #pragma unroll
                for (int rt = 0; rt < 4; ++rt)
                    accA[rt][h * 2 + i] = __builtin_amdgcn_mfma_f32_16x16x32_bf16(af[rt], wb[i * 4 + ks], accA[rt][h * 2 + i], 0, 0, 0);
        }
    }
    // ---- C: K=256 over [x|ctx] ----
    #pragma unroll
    for (int h = 0; h < 2; ++h) {        // ct-pairs
        #pragma unroll
        for (int kh = 0; kh < 2; ++kh) { // K halves (x then ctx)
            bfrag wb[8];                 // i(2) x ks2(4), batched
            #pragma unroll
            for (int i = 0; i < 2; ++i)
                #pragma unroll
                for (int ks2 = 0; ks2 < 4; ++ks2)
                    wb[i * 4 + ks2] = *(const bfrag*)(wg1t + (size_t)(nAC + (h * 2 + i) * 16 + l16) * 256 + (kh * 4 + ks2) * 32 + lk8);
            __builtin_amdgcn_sched_barrier(0);
            #pragma unroll
            for (int ks2 = 0; ks2 < 4; ++ks2) {
                const int ks = kh * 4 + ks2;
                bfrag af[4];
                #pragma unroll
                for (int rt = 0; rt < 4; ++rt)
                    af[rt] = *(const bfrag*)&XC[rt * 16 + l16][ks * 32 + lk8];
                #pragma unroll
                for (int i = 0; i < 2; ++i)
                    #pragma unroll
                    for (int rt = 0; rt < 4; ++rt)
                        accC[rt][h * 2 + i] = __builtin_amdgcn_mfma_f32_16x16x32_bf16(af[rt], wb[i * 4 + ks2], accC[rt][h * 2 + i], 0, 0, 0);
            }
        }
    }

    // ---- bias + LN stats on accA ----
    #pragma unroll
    for (int ct = 0; ct < 4; ++ct) {
        const float bb = b1[nAC + ct * 16 + l16];
        #pragma unroll
        for (int rt = 0; rt < 4; ++rt)
            #pragma unroll
            for (int r = 0; r < 4; ++r) accA[rt][ct][r] += bb;
    }
    #pragma unroll
    for (int rt = 0; rt < 4; ++rt)
        #pragma unroll
        for (int r = 0; r < 4; ++r) {
            float a = 0.f, q = 0.f;
            #pragma unroll
            for (int ct = 0; ct < 4; ++ct) {
                const float v = accA[rt][ct][r];
                a += v; q += v * v;
            }
            #pragma unroll
            for (int m = 1; m <= 8; m <<= 1) {
                a += __shfl_xor(a, m);
                q += __shfl_xor(q, m);
            }
            if (l16 == 0) {
                red1[rt * 16 + l4 + r][wid] = a;
                red2[rt * 16 + l4 + r][wid] = q;
            }
        }
    __syncthreads();
    #pragma unroll
    for (int rt = 0; rt < 4; ++rt)
        #pragma unroll
        for (int r = 0; r < 4; ++r) {
            const int row = rt * 16 + l4 + r;
            const float4 s1v = *(const float4*)&red1[row][0];
            const float4 s2v = *(const float4*)&red2[row][0];
            const float s1 = s1v.x + s1v.y + s1v.z + s1v.w;
            const float s2 = s2v.x + s2v.y + s2v.z + s2v.w;
            const float m_ = s1 * (1.f / (float)HH);
            mu[rt][r] = m_;
            rs[rt][r] = rsqrtf(s2 * (1.f / (float)HH) - m_ * m_ + EPSV);
        }

    // ---- normalize + affine + relu -> Hb (bf16, packed cvt per ct-pair) ----
    #pragma unroll
    for (int cp2 = 0; cp2 < 2; ++cp2) {
        const float g0v = lng[nAC + (2 * cp2) * 16 + l16],     b0v = lnb[nAC + (2 * cp2) * 16 + l16];
        const float g1v = lng[nAC + (2 * cp2 + 1) * 16 + l16], b1v = lnb[nAC + (2 * cp2 + 1) * 16 + l16];
        #pragma unroll
        for (int rt = 0; rt < 4; ++rt)
            #pragma unroll
            for (int r = 0; r < 4; ++r) {
                const float h0 = fmaxf((accA[rt][2 * cp2][r]     - mu[rt][r]) * rs[rt][r] * g0v + b0v, 0.f);
                const float h1 = fmaxf((accA[rt][2 * cp2 + 1][r] - mu[rt][r]) * rs[rt][r] * g1v + b1v, 0.f);
                const unsigned p = pkbf(h0, h1);
                Hb[rt * 16 + l4 + r][nAC + (2 * cp2) * 16 + l16]     = (u16)(p & 0xffffu);
                Hb[rt * 16 + l4 + r][nAC + (2 * cp2 + 1) * 16 + l16] = (u16)(p >> 16);
            }
    }
    __syncthreads();

    // ================= Phase B: P = H @ W2 + b2 ; err = emb - P  (64x128, K=256) =================
    float errv[4][2][4];
    #pragma unroll
    for (int ct = 0; ct < 2; ++ct) {
        bfrag wb[8];                        // ks(8) for this ct, batched (keeps peak pressure low)
        #pragma unroll
        for (int ks = 0; ks < 8; ++ks)
            wb[ks] = *(const bfrag*)(w2t + (size_t)(nBD + ct * 16 + l16) * 256 + ks * 32 + lk8);
        __builtin_amdgcn_sched_barrier(0);
        f32x4 acc[4];
        #pragma unroll
        for (int rt = 0; rt < 4; ++rt) acc[rt] = zf;
        #pragma unroll
        for (int ks = 0; ks < 8; ++ks) {
            bfrag af[4];
            #pragma unroll
            for (int rt = 0; rt < 4; ++rt)
                af[rt] = *(const bfrag*)&Hb[rt * 16 + l16][ks * 32 + lk8];
            #pragma unroll
            for (int rt = 0; rt < 4; ++rt)
                acc[rt] = __builtin_amdgcn_mfma_f32_16x16x32_bf16(af[rt], wb[ks], acc[rt], 0, 0, 0);
        }
        const float bb = b2[nBD + ct * 16 + l16];
        #pragma unroll
        for (int rt = 0; rt < 4; ++rt)
            #pragma unroll
            for (int r = 0; r < 4; ++r)
                errv[rt][ct][r] = ep[rt][ct][r] - (acc[rt][r] + bb);
    }

    // ---- write R = relu(accC + bg1) into XC (XC's last read was in the fused region,
    //      which every wave finished before the LN barrier -> no extra barrier needed) ----
    #pragma unroll
    for (int cp2 = 0; cp2 < 2; ++cp2) {
        const float bga = bg1[nAC + (2 * cp2) * 16 + l16];
        const float bgb = bg1[nAC + (2 * cp2 + 1) * 16 + l16];
        #pragma unroll
        for (int rt = 0; rt < 4; ++rt)
            #pragma unroll
            for (int r = 0; r < 4; ++r) {
                const float r0v = fmaxf(accC[rt][2 * cp2][r]     + bga, 0.f);
                const float r1v = fmaxf(accC[rt][2 * cp2 + 1][r] + bgb, 0.f);
                const unsigned p = pkbf(r0v, r1v);
                XC[rt * 16 + l4 + r][nAC + (2 * cp2) * 16 + l16]     = (u16)(p & 0xffffu);
                XC[rt * 16 + l4 + r][nAC + (2 * cp2 + 1) * 16 + l16] = (u16)(p >> 16);
            }
    }
    __syncthreads();   // R ready from all waves

    // ================= Phase D: G = R @ Wg2 + bg2 ; out = x + LR*sigmoid(G)*err =================
    {
        bfrag wb[16];
        #pragma unroll
        for (int ct = 0; ct < 2; ++ct)
            #pragma unroll
            for (int ks = 0; ks < 8; ++ks)
                wb[ct * 8 + ks] = *(const bfrag*)(wg2t + (size_t)(nBD + ct * 16 + l16) * 256 + ks * 32 + lk8);
        float cp[4][2][4];   // cur prefetch - flies under D's MFMAs
        #pragma unroll
        for (int rt = 0; rt < 4; ++rt)
            #pragma unroll
            for (int ct = 0; ct < 2; ++ct)
                #pragma unroll
                for (int r = 0; r < 4; ++r)
                    cp[rt][ct][r] = cur[(size_t)(g0 + rt * 16 + l4 + r) * DD + nBD + ct * 16 + l16];
        __builtin_amdgcn_sched_barrier(0);
        f32x4 acc[4][2];
        #pragma unroll
        for (int rt = 0; rt < 4; ++rt) { acc[rt][0] = zf; acc[rt][1] = zf; }
        #pragma unroll
        for (int ks = 0; ks < 8; ++ks) {
            bfrag af[4];
            #pragma unroll
            for (int rt = 0; rt < 4; ++rt)
                af[rt] = *(const bfrag*)&XC[rt * 16 + l16][ks * 32 + lk8];
            #pragma unroll
            for (int ct = 0; ct < 2; ++ct)
                #pragma unroll
                for (int rt = 0; rt < 4; ++rt)
                    acc[rt][ct] = __builtin_amdgcn_mfma_f32_16x16x32_bf16(af[rt], wb[ct * 8 + ks], acc[rt][ct], 0, 0, 0);
        }
        #pragma unroll
        for (int ct = 0; ct < 2; ++ct) {
            const float bb = bg2[nBD + ct * 16 + l16];
            #pragma unroll
            for (int rt = 0; rt < 4; ++rt)
                #pragma unroll
                for (int r = 0; r < 4; ++r) {
                    const float z = acc[rt][ct][r] + bb;
                    const float gate = 1.f / (1.f + __expf(-z));
                    outp[(size_t)(g0 + rt * 16 + l4 + r) * DD + nBD + ct * 16 + l16] =
                        cp[rt][ct][r] + LRATE * gate * errv[rt][ct][r];
                }
        }
    }
}

extern "C" void kernel_launch(void* const* d_in, const int* in_sizes, int n_in,
                              void* d_out, int out_size, void* d_ws, size_t ws_size,
                              hipStream_t stream) {
    const float* emb = (const float*)d_in[0];
    const float* W1  = (const float*)d_in[1];
    const float* b1  = (const float*)d_in[2];
    const float* lng = (const float*)d_in[3];
    const float* lnb = (const float*)d_in[4];
    const float* W2  = (const float*)d_in[5];
    const float* b2  = (const float*)d_in[6];
    const float* Wg1 = (const float*)d_in[7];
    const float* bg1 = (const float*)d_in[8];
    const float* Wg2 = (const float*)d_in[9];
    const float* bg2 = (const float*)d_in[10];
    float* out = (float*)d_out;

    u16*   wsw  = (u16*)d_ws;                          // 320 KB bf16 transposed weights
    float* ping = (float*)((char*)d_ws + (1 << 20));   // 64 MB refined scratch

    const u16* w1t  = wsw;
    const u16* w2t  = wsw + 32768;
    const u16* wg1t = wsw + 65536;
    const u16* wg2t = wsw + 131072;

    prep_weights<<<640, 256, 0, stream>>>(W1, W2, Wg1, Wg2, wsw);

    const dim3 grid(NTOK / TM);
    const dim3 block(THREADS);
    // refined chain: emb -> out -> ping -> out -> ping -> out
    refine_iter<<<grid, block, 0, stream>>>(emb,  emb, out,  w1t, w2t, wg1t, wg2t, b1, lng, lnb, b2, bg1, bg2);
    refine_iter<<<grid, block, 0, stream>>>(out,  emb, ping, w1t, w2t, wg1t, wg2t, b1, lng, lnb, b2, bg1, bg2);
    refine_iter<<<grid, block, 0, stream>>>(ping, emb, out,  w1t, w2t, wg1t, wg2t, b1, lng, lnb, b2, bg1, bg2);
    refine_iter<<<grid, block, 0, stream>>>(out,  emb, ping, w1t, w2t, wg1t, wg2t, b1, lng, lnb, b2, bg1, bg2);
    refine_iter<<<grid, block, 0, stream>>>(ping, emb, out,  w1t, w2t, wg1t, wg2t, b1, lng, lnb, b2, bg1, bg2);
}

// Round 17
// 611.068 us; speedup vs baseline: 1.3206x; 1.0095x over previous
//
#include <hip/hip_runtime.h>
#include <hip/hip_bf16.h>

#define BB   16
#define SS   8192
#define DD   128
#define HH   256
#define NTOK (BB * SS)
#define TM   64
#define THREADS 256
#define LRATE 0.1f
#define EPSV  1e-5f
#define XCST 264   // XC stride in shorts: [x(128)|c(128)|pad8]; reused for H then R (both 256-wide)

typedef short  bfrag __attribute__((ext_vector_type(8)));   // 8 bf16 = 4 VGPR (MFMA A/B frag)
typedef float  f32x4 __attribute__((ext_vector_type(4)));   // MFMA C/D frag
typedef unsigned short u16;

__device__ __forceinline__ u16 f2bf(float x) {
    unsigned u = __float_as_uint(x);
    unsigned r = (u + 0x7FFFu + ((u >> 16) & 1u)) >> 16;   // RTN-even
    return (u16)r;
}

// packed 2xfloat -> 2xbf16 (v_cvt_pk_bf16_f32, RNE)
__device__ __forceinline__ unsigned pkbf(float lo, float hi) {
    __hip_bfloat162 h2 = __float22bfloat162_rn(make_float2(lo, hi));
    unsigned u; __builtin_memcpy(&u, &h2, 4); return u;
}

// ---- weight prep: fp32 [K][N] -> bf16 transposed [N][K] in ws ----
// layout (shorts): W1t[256][128] @0, W2t[128][256] @32768, Wg1t[256][256] @65536, Wg2t[128][256] @131072
__global__ void prep_weights(const float* __restrict__ W1, const float* __restrict__ W2,
                             const float* __restrict__ Wg1, const float* __restrict__ Wg2,
                             u16* __restrict__ wsw) {
    int i = blockIdx.x * 256 + threadIdx.x;   // 0 .. 163839
    if (i < 32768) { int n = i >> 7, k = i & 127; wsw[i] = f2bf(W1[k * 256 + n]); return; }
    i -= 32768;
    if (i < 32768) { int n = i >> 8, k = i & 255; wsw[32768 + n * 256 + k] = f2bf(W2[k * 128 + n]); return; }
    i -= 32768;
    if (i < 65536) { int n = i >> 8, k = i & 255; wsw[65536 + n * 256 + k] = f2bf(Wg1[k * 256 + n]); return; }
    i -= 65536;
    { int n = i >> 8, k = i & 255; wsw[131072 + n * 256 + k] = f2bf(Wg2[k * 128 + n]); }
}

__global__ __launch_bounds__(THREADS, 2)
void refine_iter(const float* __restrict__ cur, const float* __restrict__ emb,
                 float* __restrict__ outp,
                 const u16* __restrict__ w1t, const u16* __restrict__ w2t,
                 const u16* __restrict__ wg1t, const u16* __restrict__ wg2t,
                 const float* __restrict__ b1, const float* __restrict__ lng,
                 const float* __restrict__ lnb, const float* __restrict__ b2,
                 const float* __restrict__ bg1, const float* __restrict__ bg2)
{
    // single 33.8 KB buffer, three lives: [x|ctx] -> H -> R
    __shared__ __align__(16) u16 XC[TM][XCST];
    __shared__ float red1[TM][4];
    __shared__ float red2[TM][4];

    const int t    = threadIdx.x;
    const int g0   = blockIdx.x * TM;
    const int lane = t & 63;
    const int wid  = t >> 6;              // 4 waves; each owns ALL 64 rows x a column slice
    const int l16  = lane & 15;
    const int lk8  = (lane >> 4) * 8;     // k-offset within a 32-chunk
    const int l4   = (lane >> 4) * 4;     // D-frag row offset
    const int nAC  = wid * 64;            // A/C col slice (64 wide, ct 0..3)
    const int nBD  = wid * 32;            // B/D col slice (32 wide, ct 0..1)

    // ---- stage x tile + context tile (fp32 -> bf16, packed cvt) ----
    #pragma unroll
    for (int k = 0; k < 8; ++k) {
        const int f = t + k * THREADS;    // [0,2048)
        const int m = f >> 5;             // row 0..63
        const int o = (f & 31) * 4;
        const int gt = g0 + m;
        const int s  = gt & (SS - 1);
        const int rowbase = gt - s;
        const int sp = (s == 0) ? 1 : s - 1;
        const int sn = (s == SS - 1) ? (SS - 2) : s + 1;
        const float4 xv = *(const float4*)(cur + (size_t)gt * DD + o);
        const float4 av = *(const float4*)(cur + (size_t)(rowbase + sp) * DD + o);
        const float4 bv = *(const float4*)(cur + (size_t)(rowbase + sn) * DD + o);
        uint2 xq; xq.x = pkbf(xv.x, xv.y); xq.y = pkbf(xv.z, xv.w);
        *(uint2*)&XC[m][o] = xq;
        uint2 cq;
        cq.x = pkbf(0.5f * (av.x + bv.x), 0.5f * (av.y + bv.y));
        cq.y = pkbf(0.5f * (av.z + bv.z), 0.5f * (av.w + bv.w));
        *(uint2*)&XC[m][128 + o] = cq;
    }

    // ---- early prefetch: emb values needed by phase B (acc layout) ----
    float ep[4][2][4];
    #pragma unroll
    for (int rt = 0; rt < 4; ++rt)
        #pragma unroll
        for (int ct = 0; ct < 2; ++ct)
            #pragma unroll
            for (int r = 0; r < 4; ++r)
                ep[rt][ct][r] = emb[(size_t)(g0 + rt * 16 + l4 + r) * DD + nBD + ct * 16 + l16];
    __syncthreads();

    const f32x4 zf = {0.f, 0.f, 0.f, 0.f};
    float mu[4][4], rs[4][4];

    // ======== FUSED region: phase A (X@W1 -> accA) + phase C ([X|C]@Wg1 -> accC) ========
    // 192 MFMAs, no barrier inside; C's load batches overlap A's MFMA bursts.
    f32x4 accA[4][4];   // Y1 pre-LN
    f32x4 accC[4][4];   // gate hidden pre-relu (held in regs across LN and phase B)
    #pragma unroll
    for (int rt = 0; rt < 4; ++rt)
        #pragma unroll
        for (int ct = 0; ct < 4; ++ct) { accA[rt][ct] = zf; accC[rt][ct] = zf; }

    // ---- A: K=128 over x half ----
    #pragma unroll
    for (int h = 0; h < 2; ++h) {        // ct-pairs
        bfrag wb[8];                     // i(2) x ks(4), batched
        #pragma unroll
        for (int i = 0; i < 2; ++i)
            #pragma unroll
            for (int ks = 0; ks < 4; ++ks)
                wb[i * 4 + ks] = *(const bfrag*)(w1t + (size_t)(nAC + (h * 2 + i) * 16 + l16) * 128 + ks * 32 + lk8);
        __builtin_amdgcn_sched_barrier(0);
        #pragma unroll
        for (int ks = 0; ks < 4; ++ks) {
            bfrag af[4];
            #pragma unroll
            for (int rt = 0; rt < 4; ++rt)
                af[rt] = *(const bfrag*)&XC[rt * 16 + l16][ks * 32 + lk8];
            #pragma unroll
            for (int i = 0; i < 2; ++i)
                #pragma unroll
                for (int rt = 0; rt < 4; ++rt)
                    accA[rt][h * 2 + i] = __builtin_amdgcn_mfma_f32_16x16x32_bf16(af[rt], wb[i * 4 + ks], accA[rt][h * 2 + i], 0, 0, 0);
        }
    }
    // ---- C: K=256 over [x|ctx] ----
    #pragma unroll
    for (int h = 0; h < 2; ++h) {        // ct-pairs
        #pragma unroll
        for (int kh = 0; kh < 2; ++kh) { // K halves (x then ctx)
            bfrag wb[8];                 // i(2) x ks2(4), batched
            #pragma unroll
            for (int i = 0; i < 2; ++i)
                #pragma unroll
                for (int ks2 = 0; ks2 < 4; ++ks2)
                    wb[i * 4 + ks2] = *(const bfrag*)(wg1t + (size_t)(nAC + (h * 2 + i) * 16 + l16) * 256 + (kh * 4 + ks2) * 32 + lk8);
            __builtin_amdgcn_sched_barrier(0);
            #pragma unroll
            for (int ks2 = 0; ks2 < 4; ++ks2) {
                const int ks = kh * 4 + ks2;
                bfrag af[4];
                #pragma unroll
                for (int rt = 0; rt < 4; ++rt)
                    af[rt] = *(const bfrag*)&XC[rt * 16 + l16][ks * 32 + lk8];
                #pragma unroll
                for (int i = 0; i < 2; ++i)
                    #pragma unroll
                    for (int rt = 0; rt < 4; ++rt)
                        accC[rt][h * 2 + i] = __builtin_amdgcn_mfma_f32_16x16x32_bf16(af[rt], wb[i * 4 + ks2], accC[rt][h * 2 + i], 0, 0, 0);
            }
        }
    }

    // ---- bias + LN stats on accA ----
    #pragma unroll
    for (int ct = 0; ct < 4; ++ct) {
        const float bb = b1[nAC + ct * 16 + l16];
        #pragma unroll
        for (int rt = 0; rt < 4; ++rt)
            #pragma unroll
            for (int r = 0; r < 4; ++r) accA[rt][ct][r] += bb;
    }
    #pragma unroll
    for (int rt = 0; rt < 4; ++rt)
        #pragma unroll
        for (int r = 0; r < 4; ++r) {
            float a = 0.f, q = 0.f;
            #pragma unroll
            for (int ct = 0; ct < 4; ++ct) {
                const float v = accA[rt][ct][r];
                a += v; q += v * v;
            }
            #pragma unroll
            for (int m = 1; m <= 8; m <<= 1) {
                a += __shfl_xor(a, m);
                q += __shfl_xor(q, m);
            }
            if (l16 == 0) {
                red1[rt * 16 + l4 + r][wid] = a;
                red2[rt * 16 + l4 + r][wid] = q;
            }
        }
    __syncthreads();   // LN stats ready; also: ALL fused-region XC reads drained chip-wide
    #pragma unroll
    for (int rt = 0; rt < 4; ++rt)
        #pragma unroll
        for (int r = 0; r < 4; ++r) {
            const int row = rt * 16 + l4 + r;
            const float4 s1v = *(const float4*)&red1[row][0];
            const float4 s2v = *(const float4*)&red2[row][0];
            const float s1 = s1v.x + s1v.y + s1v.z + s1v.w;
            const float s2 = s2v.x + s2v.y + s2v.z + s2v.w;
            const float m_ = s1 * (1.f / (float)HH);
            mu[rt][r] = m_;
            rs[rt][r] = rsqrtf(s2 * (1.f / (float)HH) - m_ * m_ + EPSV);
        }

    // ---- normalize + affine + relu -> H into XC (overwrites dead [x|ctx]) ----
    #pragma unroll
    for (int cp2 = 0; cp2 < 2; ++cp2) {
        const float g0v = lng[nAC + (2 * cp2) * 16 + l16],     b0v = lnb[nAC + (2 * cp2) * 16 + l16];
        const float g1v = lng[nAC + (2 * cp2 + 1) * 16 + l16], b1v = lnb[nAC + (2 * cp2 + 1) * 16 + l16];
        #pragma unroll
        for (int rt = 0; rt < 4; ++rt)
            #pragma unroll
            for (int r = 0; r < 4; ++r) {
                const float h0 = fmaxf((accA[rt][2 * cp2][r]     - mu[rt][r]) * rs[rt][r] * g0v + b0v, 0.f);
                const float h1 = fmaxf((accA[rt][2 * cp2 + 1][r] - mu[rt][r]) * rs[rt][r] * g1v + b1v, 0.f);
                const unsigned p = pkbf(h0, h1);
                XC[rt * 16 + l4 + r][nAC + (2 * cp2) * 16 + l16]     = (u16)(p & 0xffffu);
                XC[rt * 16 + l4 + r][nAC + (2 * cp2 + 1) * 16 + l16] = (u16)(p >> 16);
            }
    }
    __syncthreads();   // H ready

    // ================= Phase B: P = H @ W2 + b2 ; err = emb - P  (64x128, K=256) =================
    float errv[4][2][4];
    #pragma unroll
    for (int ct = 0; ct < 2; ++ct) {
        bfrag wb[8];                        // ks(8) for this ct, batched
        #pragma unroll
        for (int ks = 0; ks < 8; ++ks)
            wb[ks] = *(const bfrag*)(w2t + (size_t)(nBD + ct * 16 + l16) * 256 + ks * 32 + lk8);
        __builtin_amdgcn_sched_barrier(0);
        f32x4 acc[4];
        #pragma unroll
        for (int rt = 0; rt < 4; ++rt) acc[rt] = zf;
        #pragma unroll
        for (int ks = 0; ks < 8; ++ks) {
            bfrag af[4];
            #pragma unroll
            for (int rt = 0; rt < 4; ++rt)
                af[rt] = *(const bfrag*)&XC[rt * 16 + l16][ks * 32 + lk8];
            #pragma unroll
            for (int rt = 0; rt < 4; ++rt)
                acc[rt] = __builtin_amdgcn_mfma_f32_16x16x32_bf16(af[rt], wb[ks], acc[rt], 0, 0, 0);
        }
        const float bb = b2[nBD + ct * 16 + l16];
        #pragma unroll
        for (int rt = 0; rt < 4; ++rt)
            #pragma unroll
            for (int r = 0; r < 4; ++r)
                errv[rt][ct][r] = ep[rt][ct][r] - (acc[rt][r] + bb);
    }
    __syncthreads();   // all phase-B reads of XC(H) done

    // ---- write R = relu(accC + bg1) into XC ----
    #pragma unroll
    for (int cp2 = 0; cp2 < 2; ++cp2) {
        const float bga = bg1[nAC + (2 * cp2) * 16 + l16];
        const float bgb = bg1[nAC + (2 * cp2 + 1) * 16 + l16];
        #pragma unroll
        for (int rt = 0; rt < 4; ++rt)
            #pragma unroll
            for (int r = 0; r < 4; ++r) {
                const float r0v = fmaxf(accC[rt][2 * cp2][r]     + bga, 0.f);
                const float r1v = fmaxf(accC[rt][2 * cp2 + 1][r] + bgb, 0.f);
                const unsigned p = pkbf(r0v, r1v);
                XC[rt * 16 + l4 + r][nAC + (2 * cp2) * 16 + l16]     = (u16)(p & 0xffffu);
                XC[rt * 16 + l4 + r][nAC + (2 * cp2 + 1) * 16 + l16] = (u16)(p >> 16);
            }
    }
    __syncthreads();   // R ready

    // ================= Phase D: G = R @ Wg2 + bg2 ; out = x + LR*sigmoid(G)*err =================
    {
        bfrag wb[16];
        #pragma unroll
        for (int ct = 0; ct < 2; ++ct)
            #pragma unroll
            for (int ks = 0; ks < 8; ++ks)
                wb[ct * 8 + ks] = *(const bfrag*)(wg2t + (size_t)(nBD + ct * 16 + l16) * 256 + ks * 32 + lk8);
        float cp[4][2][4];   // cur prefetch - flies under D's MFMAs
        #pragma unroll
        for (int rt = 0; rt < 4; ++rt)
            #pragma unroll
            for (int ct = 0; ct < 2; ++ct)
                #pragma unroll
                for (int r = 0; r < 4; ++r)
                    cp[rt][ct][r] = cur[(size_t)(g0 + rt * 16 + l4 + r) * DD + nBD + ct * 16 + l16];
        __builtin_amdgcn_sched_barrier(0);
        f32x4 acc[4][2];
        #pragma unroll
        for (int rt = 0; rt < 4; ++rt) { acc[rt][0] = zf; acc[rt][1] = zf; }
        #pragma unroll
        for (int ks = 0; ks < 8; ++ks) {
            bfrag af[4];
            #pragma unroll
            for (int rt = 0; rt < 4; ++rt)
                af[rt] = *(const bfrag*)&XC[rt * 16 + l16][ks * 32 + lk8];
            #pragma unroll
            for (int ct = 0; ct < 2; ++ct)
                #pragma unroll
                for (int rt = 0; rt < 4; ++rt)
                    acc[rt][ct] = __builtin_amdgcn_mfma_f32_16x16x32_bf16(af[rt], wb[ct * 8 + ks], acc[rt][ct], 0, 0, 0);
        }
        #pragma unroll
        for (int ct = 0; ct < 2; ++ct) {
            const float bb = bg2[nBD + ct * 16 + l16];
            #pragma unroll
            for (int rt = 0; rt < 4; ++rt)
                #pragma unroll
                for (int r = 0; r < 4; ++r) {
                    const float z = acc[rt][ct][r] + bb;
                    const float gate = 1.f / (1.f + __expf(-z));
                    outp[(size_t)(g0 + rt * 16 + l4 + r) * DD + nBD + ct * 16 + l16] =
                        cp[rt][ct][r] + LRATE * gate * errv[rt][ct][r];
                }
        }
    }
}

extern "C" void kernel_launch(void* const* d_in, const int* in_sizes, int n_in,
                              void* d_out, int out_size, void* d_ws, size_t ws_size,
                              hipStream_t stream) {
    const float* emb = (const float*)d_in[0];
    const float* W1  = (const float*)d_in[1];
    const float* b1  = (const float*)d_in[2];
    const float* lng = (const float*)d_in[3];
    const float* lnb = (const float*)d_in[4];
    const float* W2  = (const float*)d_in[5];
    const float* b2  = (const float*)d_in[6];
    const float* Wg1 = (const float*)d_in[7];
    const float* bg1 = (const float*)d_in[8];
    const float* Wg2 = (const float*)d_in[9];
    const float* bg2 = (const float*)d_in[10];
    float* out = (float*)d_out;

    u16*   wsw  = (u16*)d_ws;                          // 320 KB bf16 transposed weights
    float* ping = (float*)((char*)d_ws + (1 << 20));   // 64 MB refined scratch

    const u16* w1t  = wsw;
    const u16* w2t  = wsw + 32768;
    const u16* wg1t = wsw + 65536;
    const u16* wg2t = wsw + 131072;

    prep_weights<<<640, 256, 0, stream>>>(W1, W2, Wg1, Wg2, wsw);

    const dim3 grid(NTOK / TM);
    const dim3 block(THREADS);
    // refined chain: emb -> out -> ping -> out -> ping -> out
    refine_iter<<<grid, block, 0, stream>>>(emb,  emb, out,  w1t, w2t, wg1t, wg2t, b1, lng, lnb, b2, bg1, bg2);
    refine_iter<<<grid, block, 0, stream>>>(out,  emb, ping, w1t, w2t, wg1t, wg2t, b1, lng, lnb, b2, bg1, bg2);
    refine_iter<<<grid, block, 0, stream>>>(ping, emb, out,  w1t, w2t, wg1t, wg2t, b1, lng, lnb, b2, bg1, bg2);
    refine_iter<<<grid, block, 0, stream>>>(out,  emb, ping, w1t, w2t, wg1t, wg2t, b1, lng, lnb, b2, bg1, bg2);
    refine_iter<<<grid, block, 0, stream>>>(ping, emb, out,  w1t, w2t, wg1t, wg2t, b1, lng, lnb, b2, bg1, bg2);
}

// Round 18
// 590.820 us; speedup vs baseline: 1.3658x; 1.0343x over previous
//
#include <hip/hip_runtime.h>
#include <hip/hip_bf16.h>

#define BB   16
#define SS   8192
#define DD   128
#define HH   256
#define NTOK (BB * SS)
#define TM   64
#define THREADS 256
#define LRATE 0.1f
#define EPSV  1e-5f
#define XCST 264   // XC stride in shorts: [x(128)|c(128)|pad8]; reused for H then R

typedef short  bfrag __attribute__((ext_vector_type(8)));   // 8 bf16 = 4 VGPR (MFMA A/B frag)
typedef float  f32x4 __attribute__((ext_vector_type(4)));   // MFMA C/D frag
typedef unsigned short u16;

__device__ __forceinline__ u16 f2bf(float x) {
    unsigned u = __float_as_uint(x);
    unsigned r = (u + 0x7FFFu + ((u >> 16) & 1u)) >> 16;   // RTN-even
    return (u16)r;
}

// packed 2xfloat -> 2xbf16 (v_cvt_pk_bf16_f32, RNE)
__device__ __forceinline__ unsigned pkbf(float lo, float hi) {
    __hip_bfloat162 h2 = __float22bfloat162_rn(make_float2(lo, hi));
    unsigned u; __builtin_memcpy(&u, &h2, 4); return u;
}

// ---- weight prep: fp32 [K][N] -> bf16 transposed [N][K] in ws ----
// layout (shorts): W1t[256][128] @0, W2t[128][256] @32768, Wg1t[256][256] @65536, Wg2t[128][256] @131072
__global__ void prep_weights(const float* __restrict__ W1, const float* __restrict__ W2,
                             const float* __restrict__ Wg1, const float* __restrict__ Wg2,
                             u16* __restrict__ wsw) {
    int i = blockIdx.x * 256 + threadIdx.x;   // 0 .. 163839
    if (i < 32768) { int n = i >> 7, k = i & 127; wsw[i] = f2bf(W1[k * 256 + n]); return; }
    i -= 32768;
    if (i < 32768) { int n = i >> 8, k = i & 255; wsw[32768 + n * 256 + k] = f2bf(W2[k * 128 + n]); return; }
    i -= 32768;
    if (i < 65536) { int n = i >> 8, k = i & 255; wsw[65536 + n * 256 + k] = f2bf(Wg1[k * 256 + n]); return; }
    i -= 65536;
    { int n = i >> 8, k = i & 255; wsw[131072 + n * 256 + k] = f2bf(Wg2[k * 128 + n]); }
}

__global__ __launch_bounds__(THREADS, 2)
void refine_iter(const float* __restrict__ cur, const float* __restrict__ emb,
                 float* __restrict__ outp,
                 const u16* __restrict__ w1t, const u16* __restrict__ w2t,
                 const u16* __restrict__ wg1t, const u16* __restrict__ wg2t,
                 const float* __restrict__ b1, const float* __restrict__ lng,
                 const float* __restrict__ lnb, const float* __restrict__ b2,
                 const float* __restrict__ bg1, const float* __restrict__ bg2)
{
    // single 33.8 KB buffer, three lives: [x|ctx] -> H -> R
    __shared__ __align__(16) u16 XC[TM][XCST];
    __shared__ float red1[TM][4];
    __shared__ float red2[TM][4];

    const int t    = threadIdx.x;
    // XCD-bijective swizzle (nwg=2048, divisible by 8): XCD k owns contiguous token chunk k.
    // Stable across the 5 chained kernels -> iter i+1 reads hit the L2 iter i wrote.
    const int nwg  = (int)gridDim.x;
    const int cpx  = nwg >> 3;
    const int bid  = (int)blockIdx.x;
    const int swz  = (bid & 7) * cpx + (bid >> 3);
    const int g0   = swz * TM;
    const int lane = t & 63;
    const int wid  = t >> 6;              // 4 waves; each owns ALL 64 rows x a column slice
    const int l16  = lane & 15;
    const int lk8  = (lane >> 4) * 8;     // k-offset within a 32-chunk
    const int l4   = (lane >> 4) * 4;     // D-frag row offset
    const int nAC  = wid * 64;            // A/C col slice (64 wide, ct 0..3)
    const int nBD  = wid * 32;            // B/D col slice (32 wide, ct 0..1)

    // ---- stage x tile + context tile (fp32 -> bf16, packed cvt) ----
    #pragma unroll
    for (int k = 0; k < 8; ++k) {
        const int f = t + k * THREADS;    // [0,2048)
        const int m = f >> 5;             // row 0..63
        const int o = (f & 31) * 4;
        const int gt = g0 + m;
        const int s  = gt & (SS - 1);
        const int rowbase = gt - s;
        const int sp = (s == 0) ? 1 : s - 1;
        const int sn = (s == SS - 1) ? (SS - 2) : s + 1;
        const float4 xv = *(const float4*)(cur + (size_t)gt * DD + o);
        const float4 av = *(const float4*)(cur + (size_t)(rowbase + sp) * DD + o);
        const float4 bv = *(const float4*)(cur + (size_t)(rowbase + sn) * DD + o);
        uint2 xq; xq.x = pkbf(xv.x, xv.y); xq.y = pkbf(xv.z, xv.w);
        *(uint2*)&XC[m][o] = xq;
        uint2 cq;
        cq.x = pkbf(0.5f * (av.x + bv.x), 0.5f * (av.y + bv.y));
        cq.y = pkbf(0.5f * (av.z + bv.z), 0.5f * (av.w + bv.w));
        *(uint2*)&XC[m][128 + o] = cq;
    }

    // ---- early prefetch: emb values needed by phase B (acc layout) ----
    float ep[4][2][4];
    #pragma unroll
    for (int rt = 0; rt < 4; ++rt)
        #pragma unroll
        for (int ct = 0; ct < 2; ++ct)
            #pragma unroll
            for (int r = 0; r < 4; ++r)
                ep[rt][ct][r] = emb[(size_t)(g0 + rt * 16 + l4 + r) * DD + nBD + ct * 16 + l16];
    __syncthreads();

    const f32x4 zf = {0.f, 0.f, 0.f, 0.f};
    float mu[4][4], rs[4][4];

    // ======== FUSED region: phase A (X@W1 -> accA) + phase C ([X|C]@Wg1 -> accC) ========
    f32x4 accA[4][4];   // Y1 pre-LN
    f32x4 accC[4][4];   // gate hidden pre-relu (held in regs across LN and phase B)
    #pragma unroll
    for (int rt = 0; rt < 4; ++rt)
        #pragma unroll
        for (int ct = 0; ct < 4; ++ct) { accA[rt][ct] = zf; accC[rt][ct] = zf; }

    // ---- A: K=128 over x half ----
    #pragma unroll
    for (int h = 0; h < 2; ++h) {        // ct-pairs
        bfrag wb[8];                     // i(2) x ks(4), batched
        #pragma unroll
        for (int i = 0; i < 2; ++i)
            #pragma unroll
            for (int ks = 0; ks < 4; ++ks)
                wb[i * 4 + ks] = *(const bfrag*)(w1t + (size_t)(nAC + (h * 2 + i) * 16 + l16) * 128 + ks * 32 + lk8);
        __builtin_amdgcn_sched_barrier(0);
        __builtin_amdgcn_s_setprio(1);
        #pragma unroll
        for (int ks = 0; ks < 4; ++ks) {
            bfrag af[4];
            #pragma unroll
            for (int rt = 0; rt < 4; ++rt)
                af[rt] = *(const bfrag*)&XC[rt * 16 + l16][ks * 32 + lk8];
            #pragma unroll
            for (int i = 0; i < 2; ++i)
                #pragma unroll
                for (int rt = 0; rt < 4; ++rt)
                    accA[rt][h * 2 + i] = __builtin_amdgcn_mfma_f32_16x16x32_bf16(af[rt], wb[i * 4 + ks], accA[rt][h * 2 + i], 0, 0, 0);
        }
        __builtin_amdgcn_s_setprio(0);
    }
    // ---- C: K=256 over [x|ctx] ----
    #pragma unroll
    for (int h = 0; h < 2; ++h) {        // ct-pairs
        #pragma unroll
        for (int kh = 0; kh < 2; ++kh) { // K halves (x then ctx)
            bfrag wb[8];                 // i(2) x ks2(4), batched
            #pragma unroll
            for (int i = 0; i < 2; ++i)
                #pragma unroll
                for (int ks2 = 0; ks2 < 4; ++ks2)
                    wb[i * 4 + ks2] = *(const bfrag*)(wg1t + (size_t)(nAC + (h * 2 + i) * 16 + l16) * 256 + (kh * 4 + ks2) * 32 + lk8);
            __builtin_amdgcn_sched_barrier(0);
            __builtin_amdgcn_s_setprio(1);
            #pragma unroll
            for (int ks2 = 0; ks2 < 4; ++ks2) {
                const int ks = kh * 4 + ks2;
                bfrag af[4];
                #pragma unroll
                for (int rt = 0; rt < 4; ++rt)
                    af[rt] = *(const bfrag*)&XC[rt * 16 + l16][ks * 32 + lk8];
                #pragma unroll
                for (int i = 0; i < 2; ++i)
                    #pragma unroll
                    for (int rt = 0; rt < 4; ++rt)
                        accC[rt][h * 2 + i] = __builtin_amdgcn_mfma_f32_16x16x32_bf16(af[rt], wb[i * 4 + ks2], accC[rt][h * 2 + i], 0, 0, 0);
            }
            __builtin_amdgcn_s_setprio(0);
        }
    }

    // ---- bias + LN stats on accA ----
    #pragma unroll
    for (int ct = 0; ct < 4; ++ct) {
        const float bb = b1[nAC + ct * 16 + l16];
        #pragma unroll
        for (int rt = 0; rt < 4; ++rt)
            #pragma unroll
            for (int r = 0; r < 4; ++r) accA[rt][ct][r] += bb;
    }
    #pragma unroll
    for (int rt = 0; rt < 4; ++rt)
        #pragma unroll
        for (int r = 0; r < 4; ++r) {
            float a = 0.f, q = 0.f;
            #pragma unroll
            for (int ct = 0; ct < 4; ++ct) {
                const float v = accA[rt][ct][r];
                a += v; q += v * v;
            }
            #pragma unroll
            for (int m = 1; m <= 8; m <<= 1) {
                a += __shfl_xor(a, m);
                q += __shfl_xor(q, m);
            }
            if (l16 == 0) {
                red1[rt * 16 + l4 + r][wid] = a;
                red2[rt * 16 + l4 + r][wid] = q;
            }
        }
    __syncthreads();   // LN stats ready; all fused-region XC reads drained
    #pragma unroll
    for (int rt = 0; rt < 4; ++rt)
        #pragma unroll
        for (int r = 0; r < 4; ++r) {
            const int row = rt * 16 + l4 + r;
            const float4 s1v = *(const float4*)&red1[row][0];
            const float4 s2v = *(const float4*)&red2[row][0];
            const float s1 = s1v.x + s1v.y + s1v.z + s1v.w;
            const float s2 = s2v.x + s2v.y + s2v.z + s2v.w;
            const float m_ = s1 * (1.f / (float)HH);
            mu[rt][r] = m_;
            rs[rt][r] = rsqrtf(s2 * (1.f / (float)HH) - m_ * m_ + EPSV);
        }

    // ---- normalize + affine + relu -> H into XC (overwrites dead [x|ctx]) ----
    #pragma unroll
    for (int cp2 = 0; cp2 < 2; ++cp2) {
        const float g0v = lng[nAC + (2 * cp2) * 16 + l16],     b0v = lnb[nAC + (2 * cp2) * 16 + l16];
        const float g1v = lng[nAC + (2 * cp2 + 1) * 16 + l16], b1v = lnb[nAC + (2 * cp2 + 1) * 16 + l16];
        #pragma unroll
        for (int rt = 0; rt < 4; ++rt)
            #pragma unroll
            for (int r = 0; r < 4; ++r) {
                const float h0 = fmaxf((accA[rt][2 * cp2][r]     - mu[rt][r]) * rs[rt][r] * g0v + b0v, 0.f);
                const float h1 = fmaxf((accA[rt][2 * cp2 + 1][r] - mu[rt][r]) * rs[rt][r] * g1v + b1v, 0.f);
                const unsigned p = pkbf(h0, h1);
                XC[rt * 16 + l4 + r][nAC + (2 * cp2) * 16 + l16]     = (u16)(p & 0xffffu);
                XC[rt * 16 + l4 + r][nAC + (2 * cp2 + 1) * 16 + l16] = (u16)(p >> 16);
            }
    }
    __syncthreads();   // H ready

    // ================= Phase B: P = H @ W2 + b2 ; err = emb - P  (64x128, K=256) =================
    float errv[4][2][4];
    #pragma unroll
    for (int ct = 0; ct < 2; ++ct) {
        bfrag wb[8];                        // ks(8) for this ct, batched
        #pragma unroll
        for (int ks = 0; ks < 8; ++ks)
            wb[ks] = *(const bfrag*)(w2t + (size_t)(nBD + ct * 16 + l16) * 256 + ks * 32 + lk8);
        __builtin_amdgcn_sched_barrier(0);
        f32x4 acc[4];
        #pragma unroll
        for (int rt = 0; rt < 4; ++rt) acc[rt] = zf;
        __builtin_amdgcn_s_setprio(1);
        #pragma unroll
        for (int ks = 0; ks < 8; ++ks) {
            bfrag af[4];
            #pragma unroll
            for (int rt = 0; rt < 4; ++rt)
                af[rt] = *(const bfrag*)&XC[rt * 16 + l16][ks * 32 + lk8];
            #pragma unroll
            for (int rt = 0; rt < 4; ++rt)
                acc[rt] = __builtin_amdgcn_mfma_f32_16x16x32_bf16(af[rt], wb[ks], acc[rt], 0, 0, 0);
        }
        __builtin_amdgcn_s_setprio(0);
        const float bb = b2[nBD + ct * 16 + l16];
        #pragma unroll
        for (int rt = 0; rt < 4; ++rt)
            #pragma unroll
            for (int r = 0; r < 4; ++r)
                errv[rt][ct][r] = ep[rt][ct][r] - (acc[rt][r] + bb);
    }
    __syncthreads();   // all phase-B reads of XC(H) done

    // ---- write R = relu(accC + bg1) into XC ----
    #pragma unroll
    for (int cp2 = 0; cp2 < 2; ++cp2) {
        const float bga = bg1[nAC + (2 * cp2) * 16 + l16];
        const float bgb = bg1[nAC + (2 * cp2 + 1) * 16 + l16];
        #pragma unroll
        for (int rt = 0; rt < 4; ++rt)
            #pragma unroll
            for (int r = 0; r < 4; ++r) {
                const float r0v = fmaxf(accC[rt][2 * cp2][r]     + bga, 0.f);
                const float r1v = fmaxf(accC[rt][2 * cp2 + 1][r] + bgb, 0.f);
                const unsigned p = pkbf(r0v, r1v);
                XC[rt * 16 + l4 + r][nAC + (2 * cp2) * 16 + l16]     = (u16)(p & 0xffffu);
                XC[rt * 16 + l4 + r][nAC + (2 * cp2 + 1) * 16 + l16] = (u16)(p >> 16);
            }
    }
    __syncthreads();   // R ready

    // ================= Phase D: G = R @ Wg2 + bg2 ; out = x + LR*sigmoid(G)*err =================
    {
        bfrag wb[16];
        #pragma unroll
        for (int ct = 0; ct < 2; ++ct)
            #pragma unroll
            for (int ks = 0; ks < 8; ++ks)
                wb[ct * 8 + ks] = *(const bfrag*)(wg2t + (size_t)(nBD + ct * 16 + l16) * 256 + ks * 32 + lk8);
        float cp[4][2][4];   // cur prefetch - flies under D's MFMAs
        #pragma unroll
        for (int rt = 0; rt < 4; ++rt)
            #pragma unroll
            for (int ct = 0; ct < 2; ++ct)
                #pragma unroll
                for (int r = 0; r < 4; ++r)
                    cp[rt][ct][r] = cur[(size_t)(g0 + rt * 16 + l4 + r) * DD + nBD + ct * 16 + l16];
        __builtin_amdgcn_sched_barrier(0);
        f32x4 acc[4][2];
        #pragma unroll
        for (int rt = 0; rt < 4; ++rt) { acc[rt][0] = zf; acc[rt][1] = zf; }
        __builtin_amdgcn_s_setprio(1);
        #pragma unroll
        for (int ks = 0; ks < 8; ++ks) {
            bfrag af[4];
            #pragma unroll
            for (int rt = 0; rt < 4; ++rt)
                af[rt] = *(const bfrag*)&XC[rt * 16 + l16][ks * 32 + lk8];
            #pragma unroll
            for (int ct = 0; ct < 2; ++ct)
                #pragma unroll
                for (int rt = 0; rt < 4; ++rt)
                    acc[rt][ct] = __builtin_amdgcn_mfma_f32_16x16x32_bf16(af[rt], wb[ct * 8 + ks], acc[rt][ct], 0, 0, 0);
        }
        __builtin_amdgcn_s_setprio(0);
        #pragma unroll
        for (int ct = 0; ct < 2; ++ct) {
            const float bb = bg2[nBD + ct * 16 + l16];
            #pragma unroll
            for (int rt = 0; rt < 4; ++rt)
                #pragma unroll
                for (int r = 0; r < 4; ++r) {
                    const float z = acc[rt][ct][r] + bb;
                    const float gate = 1.f / (1.f + __expf(-z));
                    outp[(size_t)(g0 + rt * 16 + l4 + r) * DD + nBD + ct * 16 + l16] =
                        cp[rt][ct][r] + LRATE * gate * errv[rt][ct][r];
                }
        }
    }
}

extern "C" void kernel_launch(void* const* d_in, const int* in_sizes, int n_in,
                              void* d_out, int out_size, void* d_ws, size_t ws_size,
                              hipStream_t stream) {
    const float* emb = (const float*)d_in[0];
    const float* W1  = (const float*)d_in[1];
    const float* b1  = (const float*)d_in[2];
    const float* lng = (const float*)d_in[3];
    const float* lnb = (const float*)d_in[4];
    const float* W2  = (const float*)d_in[5];
    const float* b2  = (const float*)d_in[6];
    const float* Wg1 = (const float*)d_in[7];
    const float* bg1 = (const float*)d_in[8];
    const float* Wg2 = (const float*)d_in[9];
    const float* bg2 = (const float*)d_in[10];
    float* out = (float*)d_out;

    u16*   wsw  = (u16*)d_ws;                          // 320 KB bf16 transposed weights
    float* ping = (float*)((char*)d_ws + (1 << 20));   // 64 MB refined scratch

    const u16* w1t  = wsw;
    const u16* w2t  = wsw + 32768;
    const u16* wg1t = wsw + 65536;
    const u16* wg2t = wsw + 131072;

    prep_weights<<<640, 256, 0, stream>>>(W1, W2, Wg1, Wg2, wsw);

    const dim3 grid(NTOK / TM);
    const dim3 block(THREADS);
    // refined chain: emb -> out -> ping -> out -> ping -> out
    refine_iter<<<grid, block, 0, stream>>>(emb,  emb, out,  w1t, w2t, wg1t, wg2t, b1, lng, lnb, b2, bg1, bg2);
    refine_iter<<<grid, block, 0, stream>>>(out,  emb, ping, w1t, w2t, wg1t, wg2t, b1, lng, lnb, b2, bg1, bg2);
    refine_iter<<<grid, block, 0, stream>>>(ping, emb, out,  w1t, w2t, wg1t, wg2t, b1, lng, lnb, b2, bg1, bg2);
    refine_iter<<<grid, block, 0, stream>>>(out,  emb, ping, w1t, w2t, wg1t, wg2t, b1, lng, lnb, b2, bg1, bg2);
    refine_iter<<<grid, block, 0, stream>>>(ping, emb, out,  w1t, w2t, wg1t, wg2t, b1, lng, lnb, b2, bg1, bg2);
}

// Round 19
// 580.640 us; speedup vs baseline: 1.3898x; 1.0175x over previous
//
#include <hip/hip_runtime.h>
#include <hip/hip_bf16.h>

#define BB   16
#define SS   8192
#define DD   128
#define HH   256
#define NTOK (BB * SS)
#define TM   64
#define THREADS 256
#define LRATE 0.1f
#define EPSV  1e-5f
#define XCST 264   // XC stride in shorts: [x(128)|c(128)|pad8]; reused for H
#define RST  264   // Rb stride

typedef short  bfrag __attribute__((ext_vector_type(8)));   // 8 bf16 = 4 VGPR (MFMA A/B frag)
typedef float  f32x4 __attribute__((ext_vector_type(4)));   // MFMA C/D frag
typedef unsigned short u16;

__device__ __forceinline__ u16 f2bf(float x) {
    unsigned u = __float_as_uint(x);
    unsigned r = (u + 0x7FFFu + ((u >> 16) & 1u)) >> 16;   // RTN-even
    return (u16)r;
}

// packed 2xfloat -> 2xbf16 (v_cvt_pk_bf16_f32, RNE)
__device__ __forceinline__ unsigned pkbf(float lo, float hi) {
    __hip_bfloat162 h2 = __float22bfloat162_rn(make_float2(lo, hi));
    unsigned u; __builtin_memcpy(&u, &h2, 4); return u;
}

// ---- weight prep: fp32 [K][N] -> bf16 transposed [N][K] in ws ----
// layout (shorts): W1t[256][128] @0, W2t[128][256] @32768, Wg1t[256][256] @65536, Wg2t[128][256] @131072
__global__ void prep_weights(const float* __restrict__ W1, const float* __restrict__ W2,
                             const float* __restrict__ Wg1, const float* __restrict__ Wg2,
                             u16* __restrict__ wsw) {
    int i = blockIdx.x * 256 + threadIdx.x;   // 0 .. 163839
    if (i < 32768) { int n = i >> 7, k = i & 127; wsw[i] = f2bf(W1[k * 256 + n]); return; }
    i -= 32768;
    if (i < 32768) { int n = i >> 8, k = i & 255; wsw[32768 + n * 256 + k] = f2bf(W2[k * 128 + n]); return; }
    i -= 32768;
    if (i < 65536) { int n = i >> 8, k = i & 255; wsw[65536 + n * 256 + k] = f2bf(Wg1[k * 256 + n]); return; }
    i -= 65536;
    { int n = i >> 8, k = i & 255; wsw[131072 + n * 256 + k] = f2bf(Wg2[k * 128 + n]); }
}

__global__ __launch_bounds__(THREADS, 2)
void refine_iter(const float* __restrict__ cur, const float* __restrict__ emb,
                 float* __restrict__ outp,
                 const u16* __restrict__ w1t, const u16* __restrict__ w2t,
                 const u16* __restrict__ wg1t, const u16* __restrict__ wg2t,
                 const float* __restrict__ b1, const float* __restrict__ lng,
                 const float* __restrict__ lnb, const float* __restrict__ b2,
                 const float* __restrict__ bg1, const float* __restrict__ bg2)
{
    __shared__ __align__(16) u16 XC[TM][XCST];   // [x|ctx] -> H
    __shared__ __align__(16) u16 Rb[TM][RST];    // R (phase-D input)
    __shared__ float red1[TM][4];
    __shared__ float red2[TM][4];

    const int t    = threadIdx.x;
    // XCD-bijective swizzle (nwg=2048, divisible by 8); stable across the 5 chained kernels.
    const int nwg  = (int)gridDim.x;
    const int cpx  = nwg >> 3;
    const int bid  = (int)blockIdx.x;
    const int swz  = (bid & 7) * cpx + (bid >> 3);
    const int g0   = swz * TM;
    const int lane = t & 63;
    const int wid  = t >> 6;              // 4 waves; each owns ALL 64 rows x a column slice
    const int l16  = lane & 15;
    const int lk8  = (lane >> 4) * 8;     // k-offset within a 32-chunk
    const int l4   = (lane >> 4) * 4;     // D-frag row offset
    const int nAC  = wid * 64;            // A/C col slice (64 wide, ct 0..3)
    const int nBD  = wid * 32;            // B/D col slice (32 wide, ct 0..1)

    // ---- stage x tile + context tile (fp32 -> bf16, packed cvt) ----
    #pragma unroll
    for (int k = 0; k < 8; ++k) {
        const int f = t + k * THREADS;    // [0,2048)
        const int m = f >> 5;             // row 0..63
        const int o = (f & 31) * 4;
        const int gt = g0 + m;
        const int s  = gt & (SS - 1);
        const int rowbase = gt - s;
        const int sp = (s == 0) ? 1 : s - 1;
        const int sn = (s == SS - 1) ? (SS - 2) : s + 1;
        const float4 xv = *(const float4*)(cur + (size_t)gt * DD + o);
        const float4 av = *(const float4*)(cur + (size_t)(rowbase + sp) * DD + o);
        const float4 bv = *(const float4*)(cur + (size_t)(rowbase + sn) * DD + o);
        uint2 xq; xq.x = pkbf(xv.x, xv.y); xq.y = pkbf(xv.z, xv.w);
        *(uint2*)&XC[m][o] = xq;
        uint2 cq;
        cq.x = pkbf(0.5f * (av.x + bv.x), 0.5f * (av.y + bv.y));
        cq.y = pkbf(0.5f * (av.z + bv.z), 0.5f * (av.w + bv.w));
        *(uint2*)&XC[m][128 + o] = cq;
    }

    // ---- early prefetch: emb values needed by the epilogue (acc layout) ----
    float ep[4][2][4];
    #pragma unroll
    for (int rt = 0; rt < 4; ++rt)
        #pragma unroll
        for (int ct = 0; ct < 2; ++ct)
            #pragma unroll
            for (int r = 0; r < 4; ++r)
                ep[rt][ct][r] = emb[(size_t)(g0 + rt * 16 + l4 + r) * DD + nBD + ct * 16 + l16];
    __syncthreads();   // (1) stage barrier

    const f32x4 zf = {0.f, 0.f, 0.f, 0.f};
    float mu[4][4], rs[4][4];

    // ======== FUSED region 1: phase A (X@W1 -> accA) + phase C ([X|C]@Wg1 -> accC) ========
    f32x4 accA[4][4];
    f32x4 accC[4][4];
    #pragma unroll
    for (int rt = 0; rt < 4; ++rt)
        #pragma unroll
        for (int ct = 0; ct < 4; ++ct) { accA[rt][ct] = zf; accC[rt][ct] = zf; }

    // ---- A: K=128 over x half ----
    #pragma unroll
    for (int h = 0; h < 2; ++h) {        // ct-pairs
        bfrag wb[8];
        #pragma unroll
        for (int i = 0; i < 2; ++i)
            #pragma unroll
            for (int ks = 0; ks < 4; ++ks)
                wb[i * 4 + ks] = *(const bfrag*)(w1t + (size_t)(nAC + (h * 2 + i) * 16 + l16) * 128 + ks * 32 + lk8);
        __builtin_amdgcn_sched_barrier(0);
        __builtin_amdgcn_s_setprio(1);
        #pragma unroll
        for (int ks = 0; ks < 4; ++ks) {
            bfrag af[4];
            #pragma unroll
            for (int rt = 0; rt < 4; ++rt)
                af[rt] = *(const bfrag*)&XC[rt * 16 + l16][ks * 32 + lk8];
            #pragma unroll
            for (int i = 0; i < 2; ++i)
                #pragma unroll
                for (int rt = 0; rt < 4; ++rt)
                    accA[rt][h * 2 + i] = __builtin_amdgcn_mfma_f32_16x16x32_bf16(af[rt], wb[i * 4 + ks], accA[rt][h * 2 + i], 0, 0, 0);
        }
        __builtin_amdgcn_s_setprio(0);
    }
    // ---- C: K=256 over [x|ctx] ----
    #pragma unroll
    for (int h = 0; h < 2; ++h) {
        #pragma unroll
        for (int kh = 0; kh < 2; ++kh) {
            bfrag wb[8];
            #pragma unroll
            for (int i = 0; i < 2; ++i)
                #pragma unroll
                for (int ks2 = 0; ks2 < 4; ++ks2)
                    wb[i * 4 + ks2] = *(const bfrag*)(wg1t + (size_t)(nAC + (h * 2 + i) * 16 + l16) * 256 + (kh * 4 + ks2) * 32 + lk8);
            __builtin_amdgcn_sched_barrier(0);
            __builtin_amdgcn_s_setprio(1);
            #pragma unroll
            for (int ks2 = 0; ks2 < 4; ++ks2) {
                const int ks = kh * 4 + ks2;
                bfrag af[4];
                #pragma unroll
                for (int rt = 0; rt < 4; ++rt)
                    af[rt] = *(const bfrag*)&XC[rt * 16 + l16][ks * 32 + lk8];
                #pragma unroll
                for (int i = 0; i < 2; ++i)
                    #pragma unroll
                    for (int rt = 0; rt < 4; ++rt)
                        accC[rt][h * 2 + i] = __builtin_amdgcn_mfma_f32_16x16x32_bf16(af[rt], wb[i * 4 + ks2], accC[rt][h * 2 + i], 0, 0, 0);
            }
            __builtin_amdgcn_s_setprio(0);
        }
    }

    // ---- bias + LN stats on accA ----
    #pragma unroll
    for (int ct = 0; ct < 4; ++ct) {
        const float bb = b1[nAC + ct * 16 + l16];
        #pragma unroll
        for (int rt = 0; rt < 4; ++rt)
            #pragma unroll
            for (int r = 0; r < 4; ++r) accA[rt][ct][r] += bb;
    }
    #pragma unroll
    for (int rt = 0; rt < 4; ++rt)
        #pragma unroll
        for (int r = 0; r < 4; ++r) {
            float a = 0.f, q = 0.f;
            #pragma unroll
            for (int ct = 0; ct < 4; ++ct) {
                const float v = accA[rt][ct][r];
                a += v; q += v * v;
            }
            #pragma unroll
            for (int m = 1; m <= 8; m <<= 1) {
                a += __shfl_xor(a, m);
                q += __shfl_xor(q, m);
            }
            if (l16 == 0) {
                red1[rt * 16 + l4 + r][wid] = a;
                red2[rt * 16 + l4 + r][wid] = q;
            }
        }
    __syncthreads();   // (2) LN barrier; all fused-region-1 XC reads drained
    #pragma unroll
    for (int rt = 0; rt < 4; ++rt)
        #pragma unroll
        for (int r = 0; r < 4; ++r) {
            const int row = rt * 16 + l4 + r;
            const float4 s1v = *(const float4*)&red1[row][0];
            const float4 s2v = *(const float4*)&red2[row][0];
            const float s1 = s1v.x + s1v.y + s1v.z + s1v.w;
            const float s2 = s2v.x + s2v.y + s2v.z + s2v.w;
            const float m_ = s1 * (1.f / (float)HH);
            mu[rt][r] = m_;
            rs[rt][r] = rsqrtf(s2 * (1.f / (float)HH) - m_ * m_ + EPSV);
        }

    // ---- write H -> XC (overwrites dead [x|ctx]) and R -> Rb ----
    #pragma unroll
    for (int cp2 = 0; cp2 < 2; ++cp2) {
        const float g0v = lng[nAC + (2 * cp2) * 16 + l16],     b0v = lnb[nAC + (2 * cp2) * 16 + l16];
        const float g1v = lng[nAC + (2 * cp2 + 1) * 16 + l16], b1v = lnb[nAC + (2 * cp2 + 1) * 16 + l16];
        const float bga = bg1[nAC + (2 * cp2) * 16 + l16];
        const float bgb = bg1[nAC + (2 * cp2 + 1) * 16 + l16];
        #pragma unroll
        for (int rt = 0; rt < 4; ++rt)
            #pragma unroll
            for (int r = 0; r < 4; ++r) {
                const float h0 = fmaxf((accA[rt][2 * cp2][r]     - mu[rt][r]) * rs[rt][r] * g0v + b0v, 0.f);
                const float h1 = fmaxf((accA[rt][2 * cp2 + 1][r] - mu[rt][r]) * rs[rt][r] * g1v + b1v, 0.f);
                const unsigned ph = pkbf(h0, h1);
                XC[rt * 16 + l4 + r][nAC + (2 * cp2) * 16 + l16]     = (u16)(ph & 0xffffu);
                XC[rt * 16 + l4 + r][nAC + (2 * cp2 + 1) * 16 + l16] = (u16)(ph >> 16);
                const float r0v = fmaxf(accC[rt][2 * cp2][r]     + bga, 0.f);
                const float r1v = fmaxf(accC[rt][2 * cp2 + 1][r] + bgb, 0.f);
                const unsigned pr = pkbf(r0v, r1v);
                Rb[rt * 16 + l4 + r][nAC + (2 * cp2) * 16 + l16]     = (u16)(pr & 0xffffu);
                Rb[rt * 16 + l4 + r][nAC + (2 * cp2 + 1) * 16 + l16] = (u16)(pr >> 16);
            }
    }
    __syncthreads();   // (3) H and R ready

    // ---- cur prefetch for the epilogue (flies under the whole fused B+D region) ----
    float cp[4][2][4];
    #pragma unroll
    for (int rt = 0; rt < 4; ++rt)
        #pragma unroll
        for (int ct = 0; ct < 2; ++ct)
            #pragma unroll
            for (int r = 0; r < 4; ++r)
                cp[rt][ct][r] = cur[(size_t)(g0 + rt * 16 + l4 + r) * DD + nBD + ct * 16 + l16];

    // ======== FUSED region 2: phase B (H@W2 -> accB) + phase D (R@Wg2 -> accD) ========
    f32x4 accB[4][2], accD[4][2];
    #pragma unroll
    for (int rt = 0; rt < 4; ++rt) {
        accB[rt][0] = zf; accB[rt][1] = zf;
        accD[rt][0] = zf; accD[rt][1] = zf;
    }
    #pragma unroll
    for (int ct = 0; ct < 2; ++ct) {
        {   // B sub-batch: loads overlap previous MFMAs
            bfrag wb[8];
            #pragma unroll
            for (int ks = 0; ks < 8; ++ks)
                wb[ks] = *(const bfrag*)(w2t + (size_t)(nBD + ct * 16 + l16) * 256 + ks * 32 + lk8);
            __builtin_amdgcn_sched_barrier(0);
            __builtin_amdgcn_s_setprio(1);
            #pragma unroll
            for (int ks = 0; ks < 8; ++ks) {
                bfrag af[4];
                #pragma unroll
                for (int rt = 0; rt < 4; ++rt)
                    af[rt] = *(const bfrag*)&XC[rt * 16 + l16][ks * 32 + lk8];
                #pragma unroll
                for (int rt = 0; rt < 4; ++rt)
                    accB[rt][ct] = __builtin_amdgcn_mfma_f32_16x16x32_bf16(af[rt], wb[ks], accB[rt][ct], 0, 0, 0);
            }
            __builtin_amdgcn_s_setprio(0);
        }
        {   // D sub-batch
            bfrag wb[8];
            #pragma unroll
            for (int ks = 0; ks < 8; ++ks)
                wb[ks] = *(const bfrag*)(wg2t + (size_t)(nBD + ct * 16 + l16) * 256 + ks * 32 + lk8);
            __builtin_amdgcn_sched_barrier(0);
            __builtin_amdgcn_s_setprio(1);
            #pragma unroll
            for (int ks = 0; ks < 8; ++ks) {
                bfrag ar[4];
                #pragma unroll
                for (int rt = 0; rt < 4; ++rt)
                    ar[rt] = *(const bfrag*)&Rb[rt * 16 + l16][ks * 32 + lk8];
                #pragma unroll
                for (int rt = 0; rt < 4; ++rt)
                    accD[rt][ct] = __builtin_amdgcn_mfma_f32_16x16x32_bf16(ar[rt], wb[ks], accD[rt][ct], 0, 0, 0);
            }
            __builtin_amdgcn_s_setprio(0);
        }
    }

    // ================= Epilogue: err, gate, out =================
    #pragma unroll
    for (int ct = 0; ct < 2; ++ct) {
        const float bbB = b2[nBD + ct * 16 + l16];
        const float bbD = bg2[nBD + ct * 16 + l16];
        #pragma unroll
        for (int rt = 0; rt < 4; ++rt)
            #pragma unroll
            for (int r = 0; r < 4; ++r) {
                const float err  = ep[rt][ct][r] - (accB[rt][ct][r] + bbB);
                const float z    = accD[rt][ct][r] + bbD;
                const float gate = 1.f / (1.f + __expf(-z));
                outp[(size_t)(g0 + rt * 16 + l4 + r) * DD + nBD + ct * 16 + l16] =
                    cp[rt][ct][r] + LRATE * gate * err;
            }
    }
}

extern "C" void kernel_launch(void* const* d_in, const int* in_sizes, int n_in,
                              void* d_out, int out_size, void* d_ws, size_t ws_size,
                              hipStream_t stream) {
    const float* emb = (const float*)d_in[0];
    const float* W1  = (const float*)d_in[1];
    const float* b1  = (const float*)d_in[2];
    const float* lng = (const float*)d_in[3];
    const float* lnb = (const float*)d_in[4];
    const float* W2  = (const float*)d_in[5];
    const float* b2  = (const float*)d_in[6];
    const float* Wg1 = (const float*)d_in[7];
    const float* bg1 = (const float*)d_in[8];
    const float* Wg2 = (const float*)d_in[9];
    const float* bg2 = (const float*)d_in[10];
    float* out = (float*)d_out;

    u16*   wsw  = (u16*)d_ws;                          // 320 KB bf16 transposed weights
    float* ping = (float*)((char*)d_ws + (1 << 20));   // 64 MB refined scratch

    const u16* w1t  = wsw;
    const u16* w2t  = wsw + 32768;
    const u16* wg1t = wsw + 65536;
    const u16* wg2t = wsw + 131072;

    prep_weights<<<640, 256, 0, stream>>>(W1, W2, Wg1, Wg2, wsw);

    const dim3 grid(NTOK / TM);
    const dim3 block(THREADS);
    // refined chain: emb -> out -> ping -> out -> ping -> out
    refine_iter<<<grid, block, 0, stream>>>(emb,  emb, out,  w1t, w2t, wg1t, wg2t, b1, lng, lnb, b2, bg1, bg2);
    refine_iter<<<grid, block, 0, stream>>>(out,  emb, ping, w1t, w2t, wg1t, wg2t, b1, lng, lnb, b2, bg1, bg2);
    refine_iter<<<grid, block, 0, stream>>>(ping, emb, out,  w1t, w2t, wg1t, wg2t, b1, lng, lnb, b2, bg1, bg2);
    refine_iter<<<grid, block, 0, stream>>>(out,  emb, ping, w1t, w2t, wg1t, wg2t, b1, lng, lnb, b2, bg1, bg2);
    refine_iter<<<grid, block, 0, stream>>>(ping, emb, out,  w1t, w2t, wg1t, wg2t, b1, lng, lnb, b2, bg1, bg2);
}

// Round 20
// 579.747 us; speedup vs baseline: 1.3919x; 1.0015x over previous
//
#include <hip/hip_runtime.h>
#include <hip/hip_bf16.h>

#define BB   16
#define SS   8192
#define DD   128
#define HH   256
#define NTOK (BB * SS)
#define TM   64
#define THREADS 256
#define LRATE 0.1f
#define EPSV  1e-5f
#define XCST 264   // XC stride in shorts: [x(128)|c(128)|pad8]; reused for H
#define RST  264   // Rb stride

typedef short  bfrag __attribute__((ext_vector_type(8)));   // 8 bf16 = 4 VGPR (MFMA A/B frag)
typedef float  f32x4 __attribute__((ext_vector_type(4)));   // MFMA C/D frag
typedef unsigned short u16;

__device__ __forceinline__ u16 f2bf(float x) {
    unsigned u = __float_as_uint(x);
    unsigned r = (u + 0x7FFFu + ((u >> 16) & 1u)) >> 16;   // RTN-even
    return (u16)r;
}

// packed 2xfloat -> 2xbf16 (v_cvt_pk_bf16_f32, RNE)
__device__ __forceinline__ unsigned pkbf(float lo, float hi) {
    __hip_bfloat162 h2 = __float22bfloat162_rn(make_float2(lo, hi));
    unsigned u; __builtin_memcpy(&u, &h2, 4); return u;
}

// ---- weight prep: fp32 [K][N] -> bf16 transposed [N][K] in ws ----
// layout (shorts): W1t[256][128] @0, W2t[128][256] @32768, Wg1t[256][256] @65536, Wg2t[128][256] @131072
__global__ void prep_weights(const float* __restrict__ W1, const float* __restrict__ W2,
                             const float* __restrict__ Wg1, const float* __restrict__ Wg2,
                             u16* __restrict__ wsw) {
    int i = blockIdx.x * 256 + threadIdx.x;   // 0 .. 163839
    if (i < 32768) { int n = i >> 7, k = i & 127; wsw[i] = f2bf(W1[k * 256 + n]); return; }
    i -= 32768;
    if (i < 32768) { int n = i >> 8, k = i & 255; wsw[32768 + n * 256 + k] = f2bf(W2[k * 128 + n]); return; }
    i -= 32768;
    if (i < 65536) { int n = i >> 8, k = i & 255; wsw[65536 + n * 256 + k] = f2bf(Wg1[k * 256 + n]); return; }
    i -= 65536;
    { int n = i >> 8, k = i & 255; wsw[131072 + n * 256 + k] = f2bf(Wg2[k * 128 + n]); }
}

__global__ __launch_bounds__(THREADS, 2)
void refine_iter(const float* __restrict__ cur, const float* __restrict__ emb,
                 float* __restrict__ outp,
                 const u16* __restrict__ w1t, const u16* __restrict__ w2t,
                 const u16* __restrict__ wg1t, const u16* __restrict__ wg2t,
                 const float* __restrict__ b1, const float* __restrict__ lng,
                 const float* __restrict__ lnb, const float* __restrict__ b2,
                 const float* __restrict__ bg1, const float* __restrict__ bg2)
{
    __shared__ __align__(16) u16 XC[TM][XCST];   // [x|ctx] -> H
    __shared__ __align__(16) u16 Rb[TM][RST];    // R (phase-D input), written early
    __shared__ float red1[TM][4];
    __shared__ float red2[TM][4];

    const int t    = threadIdx.x;
    // XCD-bijective swizzle (nwg=2048, divisible by 8); stable across the 5 chained kernels.
    const int nwg  = (int)gridDim.x;
    const int cpx  = nwg >> 3;
    const int bid  = (int)blockIdx.x;
    const int swz  = (bid & 7) * cpx + (bid >> 3);
    const int g0   = swz * TM;
    const int lane = t & 63;
    const int wid  = t >> 6;              // 4 waves; each owns ALL 64 rows x a column slice
    const int l16  = lane & 15;
    const int lk8  = (lane >> 4) * 8;     // k-offset within a 32-chunk
    const int l4   = (lane >> 4) * 4;     // D-frag row offset
    const int nAC  = wid * 64;            // A/C col slice (64 wide, ct 0..3)
    const int nBD  = wid * 32;            // B/D col slice (32 wide, ct 0..1)

    // ---- stage x tile + context tile (fp32 -> bf16, packed cvt) ----
    #pragma unroll
    for (int k = 0; k < 8; ++k) {
        const int f = t + k * THREADS;    // [0,2048)
        const int m = f >> 5;             // row 0..63
        const int o = (f & 31) * 4;
        const int gt = g0 + m;
        const int s  = gt & (SS - 1);
        const int rowbase = gt - s;
        const int sp = (s == 0) ? 1 : s - 1;
        const int sn = (s == SS - 1) ? (SS - 2) : s + 1;
        const float4 xv = *(const float4*)(cur + (size_t)gt * DD + o);
        const float4 av = *(const float4*)(cur + (size_t)(rowbase + sp) * DD + o);
        const float4 bv = *(const float4*)(cur + (size_t)(rowbase + sn) * DD + o);
        uint2 xq; xq.x = pkbf(xv.x, xv.y); xq.y = pkbf(xv.z, xv.w);
        *(uint2*)&XC[m][o] = xq;
        uint2 cq;
        cq.x = pkbf(0.5f * (av.x + bv.x), 0.5f * (av.y + bv.y));
        cq.y = pkbf(0.5f * (av.z + bv.z), 0.5f * (av.w + bv.w));
        *(uint2*)&XC[m][128 + o] = cq;
    }
    __syncthreads();   // (1) stage barrier

    const f32x4 zf = {0.f, 0.f, 0.f, 0.f};
    float mu[4][4], rs[4][4];

    // ======== FUSED region 1: phase A (X@W1 -> accA) + phase C ([X|C]@Wg1 -> R, written early) ========
    f32x4 accA[4][4];
    #pragma unroll
    for (int rt = 0; rt < 4; ++rt)
        #pragma unroll
        for (int ct = 0; ct < 4; ++ct) accA[rt][ct] = zf;

    // ---- A: K=128 over x half ----
    #pragma unroll
    for (int h = 0; h < 2; ++h) {        // ct-pairs
        bfrag wb[8];
        #pragma unroll
        for (int i = 0; i < 2; ++i)
            #pragma unroll
            for (int ks = 0; ks < 4; ++ks)
                wb[i * 4 + ks] = *(const bfrag*)(w1t + (size_t)(nAC + (h * 2 + i) * 16 + l16) * 128 + ks * 32 + lk8);
        __builtin_amdgcn_sched_barrier(0);
        __builtin_amdgcn_s_setprio(1);
        #pragma unroll
        for (int ks = 0; ks < 4; ++ks) {
            bfrag af[4];
            #pragma unroll
            for (int rt = 0; rt < 4; ++rt)
                af[rt] = *(const bfrag*)&XC[rt * 16 + l16][ks * 32 + lk8];
            #pragma unroll
            for (int i = 0; i < 2; ++i)
                #pragma unroll
                for (int rt = 0; rt < 4; ++rt)
                    accA[rt][h * 2 + i] = __builtin_amdgcn_mfma_f32_16x16x32_bf16(af[rt], wb[i * 4 + ks], accA[rt][h * 2 + i], 0, 0, 0);
        }
        __builtin_amdgcn_s_setprio(0);
    }
    // ---- C: K=256 over [x|ctx]; one ct-pair accumulator live at a time, R written early ----
    #pragma unroll
    for (int h = 0; h < 2; ++h) {
        f32x4 accC[4][2];
        #pragma unroll
        for (int rt = 0; rt < 4; ++rt) { accC[rt][0] = zf; accC[rt][1] = zf; }
        #pragma unroll
        for (int kh = 0; kh < 2; ++kh) {
            bfrag wb[8];
            #pragma unroll
            for (int i = 0; i < 2; ++i)
                #pragma unroll
                for (int ks2 = 0; ks2 < 4; ++ks2)
                    wb[i * 4 + ks2] = *(const bfrag*)(wg1t + (size_t)(nAC + (h * 2 + i) * 16 + l16) * 256 + (kh * 4 + ks2) * 32 + lk8);
            __builtin_amdgcn_sched_barrier(0);
            __builtin_amdgcn_s_setprio(1);
            #pragma unroll
            for (int ks2 = 0; ks2 < 4; ++ks2) {
                const int ks = kh * 4 + ks2;
                bfrag af[4];
                #pragma unroll
                for (int rt = 0; rt < 4; ++rt)
                    af[rt] = *(const bfrag*)&XC[rt * 16 + l16][ks * 32 + lk8];
                #pragma unroll
                for (int i = 0; i < 2; ++i)
                    #pragma unroll
                    for (int rt = 0; rt < 4; ++rt)
                        accC[rt][i] = __builtin_amdgcn_mfma_f32_16x16x32_bf16(af[rt], wb[i * 4 + ks2], accC[rt][i], 0, 0, 0);
            }
            __builtin_amdgcn_s_setprio(0);
        }
        // R = relu(accC + bg1) -> Rb NOW (no LN dependency); LN barrier (2) fences before region 2 reads
        const float bga = bg1[nAC + (h * 2) * 16 + l16];
        const float bgb = bg1[nAC + (h * 2 + 1) * 16 + l16];
        #pragma unroll
        for (int rt = 0; rt < 4; ++rt)
            #pragma unroll
            for (int r = 0; r < 4; ++r) {
                const float r0v = fmaxf(accC[rt][0][r] + bga, 0.f);
                const float r1v = fmaxf(accC[rt][1][r] + bgb, 0.f);
                const unsigned pr = pkbf(r0v, r1v);
                Rb[rt * 16 + l4 + r][nAC + (h * 2) * 16 + l16]     = (u16)(pr & 0xffffu);
                Rb[rt * 16 + l4 + r][nAC + (h * 2 + 1) * 16 + l16] = (u16)(pr >> 16);
            }
    }

    // ---- bias + LN stats on accA ----
    #pragma unroll
    for (int ct = 0; ct < 4; ++ct) {
        const float bb = b1[nAC + ct * 16 + l16];
        #pragma unroll
        for (int rt = 0; rt < 4; ++rt)
            #pragma unroll
            for (int r = 0; r < 4; ++r) accA[rt][ct][r] += bb;
    }
    #pragma unroll
    for (int rt = 0; rt < 4; ++rt)
        #pragma unroll
        for (int r = 0; r < 4; ++r) {
            float a = 0.f, q = 0.f;
            #pragma unroll
            for (int ct = 0; ct < 4; ++ct) {
                const float v = accA[rt][ct][r];
                a += v; q += v * v;
            }
            #pragma unroll
            for (int m = 1; m <= 8; m <<= 1) {
                a += __shfl_xor(a, m);
                q += __shfl_xor(q, m);
            }
            if (l16 == 0) {
                red1[rt * 16 + l4 + r][wid] = a;
                red2[rt * 16 + l4 + r][wid] = q;
            }
        }
    __syncthreads();   // (2) LN barrier; XC reads drained; Rb writes visible
    #pragma unroll
    for (int rt = 0; rt < 4; ++rt)
        #pragma unroll
        for (int r = 0; r < 4; ++r) {
            const int row = rt * 16 + l4 + r;
            const float4 s1v = *(const float4*)&red1[row][0];
            const float4 s2v = *(const float4*)&red2[row][0];
            const float s1 = s1v.x + s1v.y + s1v.z + s1v.w;
            const float s2 = s2v.x + s2v.y + s2v.z + s2v.w;
            const float m_ = s1 * (1.f / (float)HH);
            mu[rt][r] = m_;
            rs[rt][r] = rsqrtf(s2 * (1.f / (float)HH) - m_ * m_ + EPSV);
        }

    // ---- write H -> XC (overwrites dead [x|ctx]) ----
    #pragma unroll
    for (int cp2 = 0; cp2 < 2; ++cp2) {
        const float g0v = lng[nAC + (2 * cp2) * 16 + l16],     b0v = lnb[nAC + (2 * cp2) * 16 + l16];
        const float g1v = lng[nAC + (2 * cp2 + 1) * 16 + l16], b1v = lnb[nAC + (2 * cp2 + 1) * 16 + l16];
        #pragma unroll
        for (int rt = 0; rt < 4; ++rt)
            #pragma unroll
            for (int r = 0; r < 4; ++r) {
                const float h0 = fmaxf((accA[rt][2 * cp2][r]     - mu[rt][r]) * rs[rt][r] * g0v + b0v, 0.f);
                const float h1 = fmaxf((accA[rt][2 * cp2 + 1][r] - mu[rt][r]) * rs[rt][r] * g1v + b1v, 0.f);
                const unsigned ph = pkbf(h0, h1);
                XC[rt * 16 + l4 + r][nAC + (2 * cp2) * 16 + l16]     = (u16)(ph & 0xffffu);
                XC[rt * 16 + l4 + r][nAC + (2 * cp2 + 1) * 16 + l16] = (u16)(ph >> 16);
            }
    }
    __syncthreads();   // (3) H ready

    // ---- ep/cp prefetch for the epilogue (issued here: fly under fused B+D region) ----
    float ep[4][2][4], cp[4][2][4];
    #pragma unroll
    for (int rt = 0; rt < 4; ++rt)
        #pragma unroll
        for (int ct = 0; ct < 2; ++ct)
            #pragma unroll
            for (int r = 0; r < 4; ++r) {
                ep[rt][ct][r] = emb[(size_t)(g0 + rt * 16 + l4 + r) * DD + nBD + ct * 16 + l16];
                cp[rt][ct][r] = cur[(size_t)(g0 + rt * 16 + l4 + r) * DD + nBD + ct * 16 + l16];
            }

    // ======== FUSED region 2: phase B (H@W2 -> accB) + phase D (R@Wg2 -> accD) ========
    f32x4 accB[4][2], accD[4][2];
    #pragma unroll
    for (int rt = 0; rt < 4; ++rt) {
        accB[rt][0] = zf; accB[rt][1] = zf;
        accD[rt][0] = zf; accD[rt][1] = zf;
    }
    #pragma unroll
    for (int ct = 0; ct < 2; ++ct) {
        {   // B sub-batch
            bfrag wb[8];
            #pragma unroll
            for (int ks = 0; ks < 8; ++ks)
                wb[ks] = *(const bfrag*)(w2t + (size_t)(nBD + ct * 16 + l16) * 256 + ks * 32 + lk8);
            __builtin_amdgcn_sched_barrier(0);
            __builtin_amdgcn_s_setprio(1);
            #pragma unroll
            for (int ks = 0; ks < 8; ++ks) {
                bfrag af[4];
                #pragma unroll
                for (int rt = 0; rt < 4; ++rt)
                    af[rt] = *(const bfrag*)&XC[rt * 16 + l16][ks * 32 + lk8];
                #pragma unroll
                for (int rt = 0; rt < 4; ++rt)
                    accB[rt][ct] = __builtin_amdgcn_mfma_f32_16x16x32_bf16(af[rt], wb[ks], accB[rt][ct], 0, 0, 0);
            }
            __builtin_amdgcn_s_setprio(0);
        }
        {   // D sub-batch
            bfrag wb[8];
            #pragma unroll
            for (int ks = 0; ks < 8; ++ks)
                wb[ks] = *(const bfrag*)(wg2t + (size_t)(nBD + ct * 16 + l16) * 256 + ks * 32 + lk8);
            __builtin_amdgcn_sched_barrier(0);
            __builtin_amdgcn_s_setprio(1);
            #pragma unroll
            for (int ks = 0; ks < 8; ++ks) {
                bfrag ar[4];
                #pragma unroll
                for (int rt = 0; rt < 4; ++rt)
                    ar[rt] = *(const bfrag*)&Rb[rt * 16 + l16][ks * 32 + lk8];
                #pragma unroll
                for (int rt = 0; rt < 4; ++rt)
                    accD[rt][ct] = __builtin_amdgcn_mfma_f32_16x16x32_bf16(ar[rt], wb[ks], accD[rt][ct], 0, 0, 0);
            }
            __builtin_amdgcn_s_setprio(0);
        }
    }

    // ================= Epilogue: err, gate, out =================
    #pragma unroll
    for (int ct = 0; ct < 2; ++ct) {
        const float bbB = b2[nBD + ct * 16 + l16];
        const float bbD = bg2[nBD + ct * 16 + l16];
        #pragma unroll
        for (int rt = 0; rt < 4; ++rt)
            #pragma unroll
            for (int r = 0; r < 4; ++r) {
                const float err  = ep[rt][ct][r] - (accB[rt][ct][r] + bbB);
                const float z    = accD[rt][ct][r] + bbD;
                const float gate = 1.f / (1.f + __expf(-z));
                outp[(size_t)(g0 + rt * 16 + l4 + r) * DD + nBD + ct * 16 + l16] =
                    cp[rt][ct][r] + LRATE * gate * err;
            }
    }
}

extern "C" void kernel_launch(void* const* d_in, const int* in_sizes, int n_in,
                              void* d_out, int out_size, void* d_ws, size_t ws_size,
                              hipStream_t stream) {
    const float* emb = (const float*)d_in[0];
    const float* W1  = (const float*)d_in[1];
    const float* b1  = (const float*)d_in[2];
    const float* lng = (const float*)d_in[3];
    const float* lnb = (const float*)d_in[4];
    const float* W2  = (const float*)d_in[5];
    const float* b2  = (const float*)d_in[6];
    const float* Wg1 = (const float*)d_in[7];
    const float* bg1 = (const float*)d_in[8];
    const float* Wg2 = (const float*)d_in[9];
    const float* bg2 = (const float*)d_in[10];
    float* out = (float*)d_out;

    u16*   wsw  = (u16*)d_ws;                          // 320 KB bf16 transposed weights
    float* ping = (float*)((char*)d_ws + (1 << 20));   // 64 MB refined scratch

    const u16* w1t  = wsw;
    const u16* w2t  = wsw + 32768;
    const u16* wg1t = wsw + 65536;
    const u16* wg2t = wsw + 131072;

    prep_weights<<<640, 256, 0, stream>>>(W1, W2, Wg1, Wg2, wsw);

    const dim3 grid(NTOK / TM);
    const dim3 block(THREADS);
    // refined chain: emb -> out -> ping -> out -> ping -> out
    refine_iter<<<grid, block, 0, stream>>>(emb,  emb, out,  w1t, w2t, wg1t, wg2t, b1, lng, lnb, b2, bg1, bg2);
    refine_iter<<<grid, block, 0, stream>>>(out,  emb, ping, w1t, w2t, wg1t, wg2t, b1, lng, lnb, b2, bg1, bg2);
    refine_iter<<<grid, block, 0, stream>>>(ping, emb, out,  w1t, w2t, wg1t, wg2t, b1, lng, lnb, b2, bg1, bg2);
    refine_iter<<<grid, block, 0, stream>>>(out,  emb, ping, w1t, w2t, wg1t, wg2t, b1, lng, lnb, b2, bg1, bg2);
    refine_iter<<<grid, block, 0, stream>>>(ping, emb, out,  w1t, w2t, wg1t, wg2t, b1, lng, lnb, b2, bg1, bg2);
}

// Round 21
// 570.262 us; speedup vs baseline: 1.4150x; 1.0166x over previous
//
#include <hip/hip_runtime.h>
#include <hip/hip_bf16.h>

#define BB   16
#define SS   8192
#define DD   128
#define HH   256
#define NTOK (BB * SS)
#define TM   64
#define THREADS 256
#define LRATE 0.1f
#define EPSV  1e-5f
#define XCST 264   // XC stride in shorts: [x(128)|c(128)|pad8]; reused for H (K-permuted)
#define RST  264   // Rb stride (K-permuted)

typedef short  bfrag __attribute__((ext_vector_type(8)));   // 8 bf16 = 4 VGPR (MFMA A/B frag)
typedef float  f32x4 __attribute__((ext_vector_type(4)));   // MFMA C/D frag
typedef unsigned short u16;

__device__ __forceinline__ u16 f2bf(float x) {
    unsigned u = __float_as_uint(x);
    unsigned r = (u + 0x7FFFu + ((u >> 16) & 1u)) >> 16;   // RTN-even
    return (u16)r;
}

// packed 2xfloat -> 2xbf16 (v_cvt_pk_bf16_f32, RNE)
__device__ __forceinline__ unsigned pkbf(float lo, float hi) {
    __hip_bfloat162 h2 = __float22bfloat162_rn(make_float2(lo, hi));
    unsigned u; __builtin_memcpy(&u, &h2, 4); return u;
}

// ---- weight prep: fp32 [K][N] -> bf16 transposed [N][K] in ws ----
// layout (shorts): W1t[256][128] @0, W2t[128][256] @32768, Wg1t[256][256] @65536, Wg2t[128][256] @131072
// W2t and Wg2t use a K-permutation within each 32-group: storage k (m=k&31) holds logical
// k_l = (k&~31) | (m&1 ? (m>>1)+16 : m>>1).  H and R are stored with the same permutation,
// so MFMA position-wise pairing is exact while H/R writes become single u32 stores.
__global__ void prep_weights(const float* __restrict__ W1, const float* __restrict__ W2,
                             const float* __restrict__ Wg1, const float* __restrict__ Wg2,
                             u16* __restrict__ wsw) {
    int i = blockIdx.x * 256 + threadIdx.x;   // 0 .. 163839
    if (i < 32768) { int n = i >> 7, k = i & 127; wsw[i] = f2bf(W1[k * 256 + n]); return; }
    i -= 32768;
    if (i < 32768) {
        int n = i >> 8, k = i & 255;
        int m = k & 31;
        int kl = (k & ~31) | ((m & 1) ? ((m >> 1) + 16) : (m >> 1));
        wsw[32768 + n * 256 + k] = f2bf(W2[kl * 128 + n]);
        return;
    }
    i -= 32768;
    if (i < 65536) { int n = i >> 8, k = i & 255; wsw[65536 + n * 256 + k] = f2bf(Wg1[k * 256 + n]); return; }
    i -= 65536;
    {
        int n = i >> 8, k = i & 255;
        int m = k & 31;
        int kl = (k & ~31) | ((m & 1) ? ((m >> 1) + 16) : (m >> 1));
        wsw[131072 + n * 256 + k] = f2bf(Wg2[kl * 128 + n]);
    }
}

__global__ __launch_bounds__(THREADS, 2)
void refine_iter(const float* __restrict__ cur, const float* __restrict__ emb,
                 float* __restrict__ outp,
                 const u16* __restrict__ w1t, const u16* __restrict__ w2t,
                 const u16* __restrict__ wg1t, const u16* __restrict__ wg2t,
                 const float* __restrict__ b1, const float* __restrict__ lng,
                 const float* __restrict__ lnb, const float* __restrict__ b2,
                 const float* __restrict__ bg1, const float* __restrict__ bg2)
{
    __shared__ __align__(16) u16 XC[TM][XCST];   // [x|ctx] -> H (K-permuted)
    __shared__ __align__(16) u16 Rb[TM][RST];    // R (K-permuted), written early
    __shared__ float red1[TM][4];
    __shared__ float red2[TM][4];

    const int t    = threadIdx.x;
    // XCD-bijective swizzle (nwg=2048, divisible by 8); stable across the 5 chained kernels.
    const int nwg  = (int)gridDim.x;
    const int cpx  = nwg >> 3;
    const int bid  = (int)blockIdx.x;
    const int swz  = (bid & 7) * cpx + (bid >> 3);
    const int g0   = swz * TM;
    const int lane = t & 63;
    const int wid  = t >> 6;              // 4 waves; each owns ALL 64 rows x a column slice
    const int l16  = lane & 15;
    const int lk8  = (lane >> 4) * 8;     // k-offset within a 32-chunk
    const int l4   = (lane >> 4) * 4;     // D-frag row offset
    const int nAC  = wid * 64;            // A/C col slice (64 wide, ct 0..3)
    const int nBD  = wid * 32;            // B/D col slice (32 wide, ct 0..1)

    // ---- stage x tile + context tile (fp32 -> bf16, packed cvt) ----
    #pragma unroll
    for (int k = 0; k < 8; ++k) {
        const int f = t + k * THREADS;    // [0,2048)
        const int m = f >> 5;             // row 0..63
        const int o = (f & 31) * 4;
        const int gt = g0 + m;
        const int s  = gt & (SS - 1);
        const int rowbase = gt - s;
        const int sp = (s == 0) ? 1 : s - 1;
        const int sn = (s == SS - 1) ? (SS - 2) : s + 1;
        const float4 xv = *(const float4*)(cur + (size_t)gt * DD + o);
        const float4 av = *(const float4*)(cur + (size_t)(rowbase + sp) * DD + o);
        const float4 bv = *(const float4*)(cur + (size_t)(rowbase + sn) * DD + o);
        uint2 xq; xq.x = pkbf(xv.x, xv.y); xq.y = pkbf(xv.z, xv.w);
        *(uint2*)&XC[m][o] = xq;
        uint2 cq;
        cq.x = pkbf(0.5f * (av.x + bv.x), 0.5f * (av.y + bv.y));
        cq.y = pkbf(0.5f * (av.z + bv.z), 0.5f * (av.w + bv.w));
        *(uint2*)&XC[m][128 + o] = cq;
    }
    __syncthreads();   // (1) stage barrier

    const f32x4 zf = {0.f, 0.f, 0.f, 0.f};
    float mu[4][4], rs[4][4];

    // ======== FUSED region 1: phase A (X@W1 -> accA) + phase C ([X|C]@Wg1 -> R, written early) ========
    f32x4 accA[4][4];
    #pragma unroll
    for (int rt = 0; rt < 4; ++rt)
        #pragma unroll
        for (int ct = 0; ct < 4; ++ct) accA[rt][ct] = zf;

    // ---- A: K=128 over x half ----
    #pragma unroll
    for (int h = 0; h < 2; ++h) {        // ct-pairs
        bfrag wb[8];
        #pragma unroll
        for (int i = 0; i < 2; ++i)
            #pragma unroll
            for (int ks = 0; ks < 4; ++ks)
                wb[i * 4 + ks] = *(const bfrag*)(w1t + (size_t)(nAC + (h * 2 + i) * 16 + l16) * 128 + ks * 32 + lk8);
        __builtin_amdgcn_sched_barrier(0);
        __builtin_amdgcn_s_setprio(1);
        #pragma unroll
        for (int ks = 0; ks < 4; ++ks) {
            bfrag af[4];
            #pragma unroll
            for (int rt = 0; rt < 4; ++rt)
                af[rt] = *(const bfrag*)&XC[rt * 16 + l16][ks * 32 + lk8];
            #pragma unroll
            for (int i = 0; i < 2; ++i)
                #pragma unroll
                for (int rt = 0; rt < 4; ++rt)
                    accA[rt][h * 2 + i] = __builtin_amdgcn_mfma_f32_16x16x32_bf16(af[rt], wb[i * 4 + ks], accA[rt][h * 2 + i], 0, 0, 0);
        }
        __builtin_amdgcn_s_setprio(0);
    }
    // ---- C: K=256 over [x|ctx]; one ct-pair accumulator live at a time, R written early ----
    #pragma unroll
    for (int h = 0; h < 2; ++h) {
        f32x4 accC[4][2];
        #pragma unroll
        for (int rt = 0; rt < 4; ++rt) { accC[rt][0] = zf; accC[rt][1] = zf; }
        #pragma unroll
        for (int kh = 0; kh < 2; ++kh) {
            bfrag wb[8];
            #pragma unroll
            for (int i = 0; i < 2; ++i)
                #pragma unroll
                for (int ks2 = 0; ks2 < 4; ++ks2)
                    wb[i * 4 + ks2] = *(const bfrag*)(wg1t + (size_t)(nAC + (h * 2 + i) * 16 + l16) * 256 + (kh * 4 + ks2) * 32 + lk8);
            __builtin_amdgcn_sched_barrier(0);
            __builtin_amdgcn_s_setprio(1);
            #pragma unroll
            for (int ks2 = 0; ks2 < 4; ++ks2) {
                const int ks = kh * 4 + ks2;
                bfrag af[4];
                #pragma unroll
                for (int rt = 0; rt < 4; ++rt)
                    af[rt] = *(const bfrag*)&XC[rt * 16 + l16][ks * 32 + lk8];
                #pragma unroll
                for (int i = 0; i < 2; ++i)
                    #pragma unroll
                    for (int rt = 0; rt < 4; ++rt)
                        accC[rt][i] = __builtin_amdgcn_mfma_f32_16x16x32_bf16(af[rt], wb[i * 4 + ks2], accC[rt][i], 0, 0, 0);
            }
            __builtin_amdgcn_s_setprio(0);
        }
        // R = relu(accC + bg1) -> Rb NOW (no LN dependency), K-permuted single u32 store
        const float bga = bg1[nAC + (h * 2) * 16 + l16];
        const float bgb = bg1[nAC + (h * 2 + 1) * 16 + l16];
        #pragma unroll
        for (int rt = 0; rt < 4; ++rt)
            #pragma unroll
            for (int r = 0; r < 4; ++r) {
                const float r0v = fmaxf(accC[rt][0][r] + bga, 0.f);
                const float r1v = fmaxf(accC[rt][1][r] + bgb, 0.f);
                *(unsigned*)&Rb[rt * 16 + l4 + r][nAC + h * 32 + 2 * l16] = pkbf(r0v, r1v);
            }
    }

    // ---- bias + LN stats on accA ----
    #pragma unroll
    for (int ct = 0; ct < 4; ++ct) {
        const float bb = b1[nAC + ct * 16 + l16];
        #pragma unroll
        for (int rt = 0; rt < 4; ++rt)
            #pragma unroll
            for (int r = 0; r < 4; ++r) accA[rt][ct][r] += bb;
    }
    #pragma unroll
    for (int rt = 0; rt < 4; ++rt)
        #pragma unroll
        for (int r = 0; r < 4; ++r) {
            float a = 0.f, q = 0.f;
            #pragma unroll
            for (int ct = 0; ct < 4; ++ct) {
                const float v = accA[rt][ct][r];
                a += v; q += v * v;
            }
            #pragma unroll
            for (int m = 1; m <= 8; m <<= 1) {
                a += __shfl_xor(a, m);
                q += __shfl_xor(q, m);
            }
            if (l16 == 0) {
                red1[rt * 16 + l4 + r][wid] = a;
                red2[rt * 16 + l4 + r][wid] = q;
            }
        }
    __syncthreads();   // (2) LN barrier; XC reads drained; Rb writes visible
    #pragma unroll
    for (int rt = 0; rt < 4; ++rt)
        #pragma unroll
        for (int r = 0; r < 4; ++r) {
            const int row = rt * 16 + l4 + r;
            const float4 s1v = *(const float4*)&red1[row][0];
            const float4 s2v = *(const float4*)&red2[row][0];
            const float s1 = s1v.x + s1v.y + s1v.z + s1v.w;
            const float s2 = s2v.x + s2v.y + s2v.z + s2v.w;
            const float m_ = s1 * (1.f / (float)HH);
            mu[rt][r] = m_;
            rs[rt][r] = rsqrtf(s2 * (1.f / (float)HH) - m_ * m_ + EPSV);
        }

    // ---- write H -> XC (overwrites dead [x|ctx]), K-permuted single u32 store ----
    #pragma unroll
    for (int cp2 = 0; cp2 < 2; ++cp2) {
        const float g0v = lng[nAC + (2 * cp2) * 16 + l16],     b0v = lnb[nAC + (2 * cp2) * 16 + l16];
        const float g1v = lng[nAC + (2 * cp2 + 1) * 16 + l16], b1v = lnb[nAC + (2 * cp2 + 1) * 16 + l16];
        #pragma unroll
        for (int rt = 0; rt < 4; ++rt)
            #pragma unroll
            for (int r = 0; r < 4; ++r) {
                const float h0 = fmaxf((accA[rt][2 * cp2][r]     - mu[rt][r]) * rs[rt][r] * g0v + b0v, 0.f);
                const float h1 = fmaxf((accA[rt][2 * cp2 + 1][r] - mu[rt][r]) * rs[rt][r] * g1v + b1v, 0.f);
                *(unsigned*)&XC[rt * 16 + l4 + r][nAC + cp2 * 32 + 2 * l16] = pkbf(h0, h1);
            }
    }
    __syncthreads();   // (3) H ready

    // ---- ep/cp prefetch for the epilogue (fly under fused B+D region) ----
    float ep[4][2][4], cp[4][2][4];
    #pragma unroll
    for (int rt = 0; rt < 4; ++rt)
        #pragma unroll
        for (int ct = 0; ct < 2; ++ct)
            #pragma unroll
            for (int r = 0; r < 4; ++r) {
                ep[rt][ct][r] = emb[(size_t)(g0 + rt * 16 + l4 + r) * DD + nBD + ct * 16 + l16];
                cp[rt][ct][r] = cur[(size_t)(g0 + rt * 16 + l4 + r) * DD + nBD + ct * 16 + l16];
            }

    // ======== FUSED region 2: phase B (H@W2 -> accB) + phase D (R@Wg2 -> accD) ========
    f32x4 accB[4][2], accD[4][2];
    #pragma unroll
    for (int rt = 0; rt < 4; ++rt) {
        accB[rt][0] = zf; accB[rt][1] = zf;
        accD[rt][0] = zf; accD[rt][1] = zf;
    }
    #pragma unroll
    for (int ct = 0; ct < 2; ++ct) {
        {   // B sub-batch
            bfrag wb[8];
            #pragma unroll
            for (int ks = 0; ks < 8; ++ks)
                wb[ks] = *(const bfrag*)(w2t + (size_t)(nBD + ct * 16 + l16) * 256 + ks * 32 + lk8);
            __builtin_amdgcn_sched_barrier(0);
            __builtin_amdgcn_s_setprio(1);
            #pragma unroll
            for (int ks = 0; ks < 8; ++ks) {
                bfrag af[4];
                #pragma unroll
                for (int rt = 0; rt < 4; ++rt)
                    af[rt] = *(const bfrag*)&XC[rt * 16 + l16][ks * 32 + lk8];
                #pragma unroll
                for (int rt = 0; rt < 4; ++rt)
                    accB[rt][ct] = __builtin_amdgcn_mfma_f32_16x16x32_bf16(af[rt], wb[ks], accB[rt][ct], 0, 0, 0);
            }
            __builtin_amdgcn_s_setprio(0);
        }
        {   // D sub-batch
            bfrag wb[8];
            #pragma unroll
            for (int ks = 0; ks < 8; ++ks)
                wb[ks] = *(const bfrag*)(wg2t + (size_t)(nBD + ct * 16 + l16) * 256 + ks * 32 + lk8);
            __builtin_amdgcn_sched_barrier(0);
            __builtin_amdgcn_s_setprio(1);
            #pragma unroll
            for (int ks = 0; ks < 8; ++ks) {
                bfrag ar[4];
                #pragma unroll
                for (int rt = 0; rt < 4; ++rt)
                    ar[rt] = *(const bfrag*)&Rb[rt * 16 + l16][ks * 32 + lk8];
                #pragma unroll
                for (int rt = 0; rt < 4; ++rt)
                    accD[rt][ct] = __builtin_amdgcn_mfma_f32_16x16x32_bf16(ar[rt], wb[ks], accD[rt][ct], 0, 0, 0);
            }
            __builtin_amdgcn_s_setprio(0);
        }
    }

    // ================= Epilogue: err, gate, out =================
    #pragma unroll
    for (int ct = 0; ct < 2; ++ct) {
        const float bbB = b2[nBD + ct * 16 + l16];
        const float bbD = bg2[nBD + ct * 16 + l16];
        #pragma unroll
        for (int rt = 0; rt < 4; ++rt)
            #pragma unroll
            for (int r = 0; r < 4; ++r) {
                const float err  = ep[rt][ct][r] - (accB[rt][ct][r] + bbB);
                const float z    = accD[rt][ct][r] + bbD;
                const float gate = 1.f / (1.f + __expf(-z));
                outp[(size_t)(g0 + rt * 16 + l4 + r) * DD + nBD + ct * 16 + l16] =
                    cp[rt][ct][r] + LRATE * gate * err;
            }
    }
}

extern "C" void kernel_launch(void* const* d_in, const int* in_sizes, int n_in,
                              void* d_out, int out_size, void* d_ws, size_t ws_size,
                              hipStream_t stream) {
    const float* emb = (const float*)d_in[0];
    const float* W1  = (const float*)d_in[1];
    const float* b1  = (const float*)d_in[2];
    const float* lng = (const float*)d_in[3];
    const float* lnb = (const float*)d_in[4];
    const float* W2  = (const float*)d_in[5];
    const float* b2  = (const float*)d_in[6];
    const float* Wg1 = (const float*)d_in[7];
    const float* bg1 = (const float*)d_in[8];
    const float* Wg2 = (const float*)d_in[9];
    const float* bg2 = (const float*)d_in[10];
    float* out = (float*)d_out;

    u16*   wsw  = (u16*)d_ws;                          // 320 KB bf16 transposed weights
    float* ping = (float*)((char*)d_ws + (1 << 20));   // 64 MB refined scratch

    const u16* w1t  = wsw;
    const u16* w2t  = wsw + 32768;
    const u16* wg1t = wsw + 65536;
    const u16* wg2t = wsw + 131072;

    prep_weights<<<640, 256, 0, stream>>>(W1, W2, Wg1, Wg2, wsw);

    const dim3 grid(NTOK / TM);
    const dim3 block(THREADS);
    // refined chain: emb -> out -> ping -> out -> ping -> out
    refine_iter<<<grid, block, 0, stream>>>(emb,  emb, out,  w1t, w2t, wg1t, wg2t, b1, lng, lnb, b2, bg1, bg2);
    refine_iter<<<grid, block, 0, stream>>>(out,  emb, ping, w1t, w2t, wg1t, wg2t, b1, lng, lnb, b2, bg1, bg2);
    refine_iter<<<grid, block, 0, stream>>>(ping, emb, out,  w1t, w2t, wg1t, wg2t, b1, lng, lnb, b2, bg1, bg2);
    refine_iter<<<grid, block, 0, stream>>>(out,  emb, ping, w1t, w2t, wg1t, wg2t, b1, lng, lnb, b2, bg1, bg2);
    refine_iter<<<grid, block, 0, stream>>>(ping, emb, out,  w1t, w2t, wg1t, wg2t, b1, lng, lnb, b2, bg1, bg2);
}

// Round 22
// 568.182 us; speedup vs baseline: 1.4202x; 1.0037x over previous
//
#include <hip/hip_runtime.h>
#include <hip/hip_bf16.h>

#define BB   16
#define SS   8192
#define DD   128
#define HH   256
#define NTOK (BB * SS)
#define TM   64
#define THREADS 256
#define LRATE 0.1f
#define EPSV  1e-5f
#define XCST 264   // XC stride in shorts: [x(128)|c(128)|pad8]; reused for H (K-permuted)
#define RST  264   // Rb stride (K-permuted)

typedef short  bfrag __attribute__((ext_vector_type(8)));   // 8 bf16 = 4 VGPR (MFMA A/B frag)
typedef float  f32x4 __attribute__((ext_vector_type(4)));   // MFMA C/D frag
typedef unsigned short u16;

__device__ __forceinline__ u16 f2bf(float x) {
    unsigned u = __float_as_uint(x);
    unsigned r = (u + 0x7FFFu + ((u >> 16) & 1u)) >> 16;   // RTN-even
    return (u16)r;
}

// packed 2xfloat -> 2xbf16 (v_cvt_pk_bf16_f32, RNE)
__device__ __forceinline__ unsigned pkbf(float lo, float hi) {
    __hip_bfloat162 h2 = __float22bfloat162_rn(make_float2(lo, hi));
    unsigned u; __builtin_memcpy(&u, &h2, 4); return u;
}

// ---- weight prep: fp32 [K][N] -> bf16 transposed [N][K] in ws ----
// layout (shorts): W1t[256][128] @0, W2t[128][256] @32768, Wg1t[256][256] @65536, Wg2t[128][256] @131072
// W2t and Wg2t use a K-permutation within each 32-group: storage k (m=k&31) holds logical
// k_l = (k&~31) | (m&1 ? (m>>1)+16 : m>>1).  H and R are stored with the same permutation.
__global__ void prep_weights(const float* __restrict__ W1, const float* __restrict__ W2,
                             const float* __restrict__ Wg1, const float* __restrict__ Wg2,
                             u16* __restrict__ wsw) {
    int i = blockIdx.x * 256 + threadIdx.x;   // 0 .. 163839
    if (i < 32768) { int n = i >> 7, k = i & 127; wsw[i] = f2bf(W1[k * 256 + n]); return; }
    i -= 32768;
    if (i < 32768) {
        int n = i >> 8, k = i & 255;
        int m = k & 31;
        int kl = (k & ~31) | ((m & 1) ? ((m >> 1) + 16) : (m >> 1));
        wsw[32768 + n * 256 + k] = f2bf(W2[kl * 128 + n]);
        return;
    }
    i -= 32768;
    if (i < 65536) { int n = i >> 8, k = i & 255; wsw[65536 + n * 256 + k] = f2bf(Wg1[k * 256 + n]); return; }
    i -= 65536;
    {
        int n = i >> 8, k = i & 255;
        int m = k & 31;
        int kl = (k & ~31) | ((m & 1) ? ((m >> 1) + 16) : (m >> 1));
        wsw[131072 + n * 256 + k] = f2bf(Wg2[kl * 128 + n]);
    }
}

__global__ __launch_bounds__(THREADS, 2)
void refine_iter(const float* __restrict__ cur, const float* __restrict__ emb,
                 float* __restrict__ outp,
                 const u16* __restrict__ w1t, const u16* __restrict__ w2t,
                 const u16* __restrict__ wg1t, const u16* __restrict__ wg2t,
                 const float* __restrict__ b1, const float* __restrict__ lng,
                 const float* __restrict__ lnb, const float* __restrict__ b2,
                 const float* __restrict__ bg1, const float* __restrict__ bg2)
{
    __shared__ __align__(16) u16 XC[TM][XCST];   // [x|ctx] -> H (K-permuted)
    __shared__ __align__(16) u16 Rb[TM][RST];    // R (K-permuted), written early
    __shared__ float red1[TM][4];
    __shared__ float red2[TM][4];

    const int t    = threadIdx.x;
    // XCD-bijective swizzle (nwg=2048, divisible by 8); stable across the 5 chained kernels.
    const int nwg  = (int)gridDim.x;
    const int cpx  = nwg >> 3;
    const int bid  = (int)blockIdx.x;
    const int swz  = (bid & 7) * cpx + (bid >> 3);
    const int g0   = swz * TM;
    const int lane = t & 63;
    const int wid  = t >> 6;              // 4 waves; each owns ALL 64 rows x a column slice
    const int l16  = lane & 15;
    const int lk8  = (lane >> 4) * 8;     // k-offset within a 32-chunk
    const int l4   = (lane >> 4) * 4;     // D-frag row offset
    const int nAC  = wid * 64;            // A/C col slice (64 wide, ct 0..3)
    const int nBD  = wid * 32;            // B/D col slice (32 wide, ct 0..1)

    // ---- stage x tile + context tile (fp32 -> bf16, packed cvt), 8 shorts/lane/iter ----
    #pragma unroll
    for (int k = 0; k < 4; ++k) {
        const int f = t + k * THREADS;    // [0,1024)
        const int m = f >> 4;             // row 0..63
        const int o = (f & 15) * 8;       // short offset in row
        const int gt = g0 + m;
        const int s  = gt & (SS - 1);
        const int rowbase = gt - s;
        const int sp = (s == 0) ? 1 : s - 1;
        const int sn = (s == SS - 1) ? (SS - 2) : s + 1;
        const float4 xv0 = *(const float4*)(cur + (size_t)gt * DD + o);
        const float4 xv1 = *(const float4*)(cur + (size_t)gt * DD + o + 4);
        const float4 av0 = *(const float4*)(cur + (size_t)(rowbase + sp) * DD + o);
        const float4 av1 = *(const float4*)(cur + (size_t)(rowbase + sp) * DD + o + 4);
        const float4 bv0 = *(const float4*)(cur + (size_t)(rowbase + sn) * DD + o);
        const float4 bv1 = *(const float4*)(cur + (size_t)(rowbase + sn) * DD + o + 4);
        uint4 xq;
        xq.x = pkbf(xv0.x, xv0.y); xq.y = pkbf(xv0.z, xv0.w);
        xq.z = pkbf(xv1.x, xv1.y); xq.w = pkbf(xv1.z, xv1.w);
        *(uint4*)&XC[m][o] = xq;
        uint4 cq;
        cq.x = pkbf(0.5f * (av0.x + bv0.x), 0.5f * (av0.y + bv0.y));
        cq.y = pkbf(0.5f * (av0.z + bv0.z), 0.5f * (av0.w + bv0.w));
        cq.z = pkbf(0.5f * (av1.x + bv1.x), 0.5f * (av1.y + bv1.y));
        cq.w = pkbf(0.5f * (av1.z + bv1.z), 0.5f * (av1.w + bv1.w));
        *(uint4*)&XC[m][128 + o] = cq;
    }
    __syncthreads();   // (1) stage barrier

    const f32x4 zf = {0.f, 0.f, 0.f, 0.f};
    float mu[4][4], rs[4][4];

    // ======== FUSED region 1: phase A (X@W1 -> accA) + phase C ([X|C]@Wg1 -> R, written early) ========
    f32x4 accA[4][4];
    #pragma unroll
    for (int rt = 0; rt < 4; ++rt)
        #pragma unroll
        for (int ct = 0; ct < 4; ++ct) accA[rt][ct] = zf;

    // ---- A: K=128 over x half ----
    #pragma unroll
    for (int h = 0; h < 2; ++h) {        // ct-pairs
        bfrag wb[8];
        #pragma unroll
        for (int i = 0; i < 2; ++i)
            #pragma unroll
            for (int ks = 0; ks < 4; ++ks)
                wb[i * 4 + ks] = *(const bfrag*)(w1t + (size_t)(nAC + (h * 2 + i) * 16 + l16) * 128 + ks * 32 + lk8);
        __builtin_amdgcn_sched_barrier(0);
        __builtin_amdgcn_s_setprio(1);
        #pragma unroll
        for (int ks = 0; ks < 4; ++ks) {
            bfrag af[4];
            #pragma unroll
            for (int rt = 0; rt < 4; ++rt)
                af[rt] = *(const bfrag*)&XC[rt * 16 + l16][ks * 32 + lk8];
            #pragma unroll
            for (int i = 0; i < 2; ++i)
                #pragma unroll
                for (int rt = 0; rt < 4; ++rt)
                    accA[rt][h * 2 + i] = __builtin_amdgcn_mfma_f32_16x16x32_bf16(af[rt], wb[i * 4 + ks], accA[rt][h * 2 + i], 0, 0, 0);
        }
        __builtin_amdgcn_s_setprio(0);
    }
    // ---- C: K=256 over [x|ctx]; one ct-pair accumulator live at a time, R written early ----
    #pragma unroll
    for (int h = 0; h < 2; ++h) {
        f32x4 accC[4][2];
        #pragma unroll
        for (int rt = 0; rt < 4; ++rt) { accC[rt][0] = zf; accC[rt][1] = zf; }
        #pragma unroll
        for (int kh = 0; kh < 2; ++kh) {
            bfrag wb[8];
            #pragma unroll
            for (int i = 0; i < 2; ++i)
                #pragma unroll
                for (int ks2 = 0; ks2 < 4; ++ks2)
                    wb[i * 4 + ks2] = *(const bfrag*)(wg1t + (size_t)(nAC + (h * 2 + i) * 16 + l16) * 256 + (kh * 4 + ks2) * 32 + lk8);
            __builtin_amdgcn_sched_barrier(0);
            __builtin_amdgcn_s_setprio(1);
            #pragma unroll
            for (int ks2 = 0; ks2 < 4; ++ks2) {
                const int ks = kh * 4 + ks2;
                bfrag af[4];
                #pragma unroll
                for (int rt = 0; rt < 4; ++rt)
                    af[rt] = *(const bfrag*)&XC[rt * 16 + l16][ks * 32 + lk8];
                #pragma unroll
                for (int i = 0; i < 2; ++i)
                    #pragma unroll
                    for (int rt = 0; rt < 4; ++rt)
                        accC[rt][i] = __builtin_amdgcn_mfma_f32_16x16x32_bf16(af[rt], wb[i * 4 + ks2], accC[rt][i], 0, 0, 0);
            }
            __builtin_amdgcn_s_setprio(0);
        }
        // R = relu(accC + bg1) -> Rb NOW (no LN dependency), K-permuted single u32 store
        const float bga = bg1[nAC + (h * 2) * 16 + l16];
        const float bgb = bg1[nAC + (h * 2 + 1) * 16 + l16];
        #pragma unroll
        for (int rt = 0; rt < 4; ++rt)
            #pragma unroll
            for (int r = 0; r < 4; ++r) {
                const float r0v = fmaxf(accC[rt][0][r] + bga, 0.f);
                const float r1v = fmaxf(accC[rt][1][r] + bgb, 0.f);
                *(unsigned*)&Rb[rt * 16 + l4 + r][nAC + h * 32 + 2 * l16] = pkbf(r0v, r1v);
            }
    }

    // ---- bias + LN stats on accA ----
    #pragma unroll
    for (int ct = 0; ct < 4; ++ct) {
        const float bb = b1[nAC + ct * 16 + l16];
        #pragma unroll
        for (int rt = 0; rt < 4; ++rt)
            #pragma unroll
            for (int r = 0; r < 4; ++r) accA[rt][ct][r] += bb;
    }
    #pragma unroll
    for (int rt = 0; rt < 4; ++rt)
        #pragma unroll
        for (int r = 0; r < 4; ++r) {
            float a = 0.f, q = 0.f;
            #pragma unroll
            for (int ct = 0; ct < 4; ++ct) {
                const float v = accA[rt][ct][r];
                a += v; q += v * v;
            }
            #pragma unroll
            for (int m = 1; m <= 8; m <<= 1) {
                a += __shfl_xor(a, m);
                q += __shfl_xor(q, m);
            }
            if (l16 == 0) {
                red1[rt * 16 + l4 + r][wid] = a;
                red2[rt * 16 + l4 + r][wid] = q;
            }
        }
    __syncthreads();   // (2) LN barrier; XC reads drained; Rb writes visible
    #pragma unroll
    for (int rt = 0; rt < 4; ++rt)
        #pragma unroll
        for (int r = 0; r < 4; ++r) {
            const int row = rt * 16 + l4 + r;
            const float4 s1v = *(const float4*)&red1[row][0];
            const float4 s2v = *(const float4*)&red2[row][0];
            const float s1 = s1v.x + s1v.y + s1v.z + s1v.w;
            const float s2 = s2v.x + s2v.y + s2v.z + s2v.w;
            const float m_ = s1 * (1.f / (float)HH);
            mu[rt][r] = m_;
            rs[rt][r] = rsqrtf(s2 * (1.f / (float)HH) - m_ * m_ + EPSV);
        }

    // ---- write H -> XC (overwrites dead [x|ctx]), K-permuted single u32 store ----
    #pragma unroll
    for (int cp2 = 0; cp2 < 2; ++cp2) {
        const float g0v = lng[nAC + (2 * cp2) * 16 + l16],     b0v = lnb[nAC + (2 * cp2) * 16 + l16];
        const float g1v = lng[nAC + (2 * cp2 + 1) * 16 + l16], b1v = lnb[nAC + (2 * cp2 + 1) * 16 + l16];
        #pragma unroll
        for (int rt = 0; rt < 4; ++rt)
            #pragma unroll
            for (int r = 0; r < 4; ++r) {
                const float h0 = fmaxf((accA[rt][2 * cp2][r]     - mu[rt][r]) * rs[rt][r] * g0v + b0v, 0.f);
                const float h1 = fmaxf((accA[rt][2 * cp2 + 1][r] - mu[rt][r]) * rs[rt][r] * g1v + b1v, 0.f);
                *(unsigned*)&XC[rt * 16 + l4 + r][nAC + cp2 * 32 + 2 * l16] = pkbf(h0, h1);
            }
    }
    __syncthreads();   // (3) H ready

    // ---- ep/cp prefetch for the epilogue (fly under fused B+D region) ----
    float ep[4][2][4], cp[4][2][4];
    #pragma unroll
    for (int rt = 0; rt < 4; ++rt)
        #pragma unroll
        for (int ct = 0; ct < 2; ++ct)
            #pragma unroll
            for (int r = 0; r < 4; ++r) {
                ep[rt][ct][r] = emb[(size_t)(g0 + rt * 16 + l4 + r) * DD + nBD + ct * 16 + l16];
                cp[rt][ct][r] = cur[(size_t)(g0 + rt * 16 + l4 + r) * DD + nBD + ct * 16 + l16];
            }

    // ======== FUSED region 2: phase B (H@W2 -> accB) + phase D (R@Wg2 -> accD) ========
    f32x4 accB[4][2], accD[4][2];
    #pragma unroll
    for (int rt = 0; rt < 4; ++rt) {
        accB[rt][0] = zf; accB[rt][1] = zf;
        accD[rt][0] = zf; accD[rt][1] = zf;
    }
    #pragma unroll
    for (int ct = 0; ct < 2; ++ct) {
        {   // B sub-batch
            bfrag wb[8];
            #pragma unroll
            for (int ks = 0; ks < 8; ++ks)
                wb[ks] = *(const bfrag*)(w2t + (size_t)(nBD + ct * 16 + l16) * 256 + ks * 32 + lk8);
            __builtin_amdgcn_sched_barrier(0);
            __builtin_amdgcn_s_setprio(1);
            #pragma unroll
            for (int ks = 0; ks < 8; ++ks) {
                bfrag af[4];
                #pragma unroll
                for (int rt = 0; rt < 4; ++rt)
                    af[rt] = *(const bfrag*)&XC[rt * 16 + l16][ks * 32 + lk8];
                #pragma unroll
                for (int rt = 0; rt < 4; ++rt)
                    accB[rt][ct] = __builtin_amdgcn_mfma_f32_16x16x32_bf16(af[rt], wb[ks], accB[rt][ct], 0, 0, 0);
            }
            __builtin_amdgcn_s_setprio(0);
        }
        {   // D sub-batch
            bfrag wb[8];
            #pragma unroll
            for (int ks = 0; ks < 8; ++ks)
                wb[ks] = *(const bfrag*)(wg2t + (size_t)(nBD + ct * 16 + l16) * 256 + ks * 32 + lk8);
            __builtin_amdgcn_sched_barrier(0);
            __builtin_amdgcn_s_setprio(1);
            #pragma unroll
            for (int ks = 0; ks < 8; ++ks) {
                bfrag ar[4];
                #pragma unroll
                for (int rt = 0; rt < 4; ++rt)
                    ar[rt] = *(const bfrag*)&Rb[rt * 16 + l16][ks * 32 + lk8];
                #pragma unroll
                for (int rt = 0; rt < 4; ++rt)
                    accD[rt][ct] = __builtin_amdgcn_mfma_f32_16x16x32_bf16(ar[rt], wb[ks], accD[rt][ct], 0, 0, 0);
            }
            __builtin_amdgcn_s_setprio(0);
        }
    }

    // ================= Epilogue: err, gate, out =================
    #pragma unroll
    for (int ct = 0; ct < 2; ++ct) {
        const float bbB = b2[nBD + ct * 16 + l16];
        const float bbD = bg2[nBD + ct * 16 + l16];
        #pragma unroll
        for (int rt = 0; rt < 4; ++rt)
            #pragma unroll
            for (int r = 0; r < 4; ++r) {
                const float err  = ep[rt][ct][r] - (accB[rt][ct][r] + bbB);
                const float z    = accD[rt][ct][r] + bbD;
                const float gate = 1.f / (1.f + __expf(-z));
                outp[(size_t)(g0 + rt * 16 + l4 + r) * DD + nBD + ct * 16 + l16] =
                    cp[rt][ct][r] + LRATE * gate * err;
            }
    }
}

extern "C" void kernel_launch(void* const* d_in, const int* in_sizes, int n_in,
                              void* d_out, int out_size, void* d_ws, size_t ws_size,
                              hipStream_t stream) {
    const float* emb = (const float*)d_in[0];
    const float* W1  = (const float*)d_in[1];
    const float* b1  = (const float*)d_in[2];
    const float* lng = (const float*)d_in[3];
    const float* lnb = (const float*)d_in[4];
    const float* W2  = (const float*)d_in[5];
    const float* b2  = (const float*)d_in[6];
    const float* Wg1 = (const float*)d_in[7];
    const float* bg1 = (const float*)d_in[8];
    const float* Wg2 = (const float*)d_in[9];
    const float* bg2 = (const float*)d_in[10];
    float* out = (float*)d_out;

    u16*   wsw  = (u16*)d_ws;                          // 320 KB bf16 transposed weights
    float* ping = (float*)((char*)d_ws + (1 << 20));   // 64 MB refined scratch

    const u16* w1t  = wsw;
    const u16* w2t  = wsw + 32768;
    const u16* wg1t = wsw + 65536;
    const u16* wg2t = wsw + 131072;

    prep_weights<<<640, 256, 0, stream>>>(W1, W2, Wg1, Wg2, wsw);

    const dim3 grid(NTOK / TM);
    const dim3 block(THREADS);
    // refined chain: emb -> out -> ping -> out -> ping -> out
    refine_iter<<<grid, block, 0, stream>>>(emb,  emb, out,  w1t, w2t, wg1t, wg2t, b1, lng, lnb, b2, bg1, bg2);
    refine_iter<<<grid, block, 0, stream>>>(out,  emb, ping, w1t, w2t, wg1t, wg2t, b1, lng, lnb, b2, bg1, bg2);
    refine_iter<<<grid, block, 0, stream>>>(ping, emb, out,  w1t, w2t, wg1t, wg2t, b1, lng, lnb, b2, bg1, bg2);
    refine_iter<<<grid, block, 0, stream>>>(out,  emb, ping, w1t, w2t, wg1t, wg2t, b1, lng, lnb, b2, bg1, bg2);
    refine_iter<<<grid, block, 0, stream>>>(ping, emb, out,  w1t, w2t, wg1t, wg2t, b1, lng, lnb, b2, bg1, bg2);
}